// Round 3
// baseline (7911.108 us; speedup 1.0000x reference)
//
#include <hip/hip_runtime.h>
#include <hip/hip_bf16.h>

typedef __bf16 bf16x8 __attribute__((ext_vector_type(8)));
typedef float f32x4 __attribute__((ext_vector_type(4)));

#define DEV static __device__ __forceinline__

constexpr int Bq = 32, Sq = 128, Tq = 64, Eq = 256, Hq = 512, Vq = 32000;
constexpr int G4 = 2048;          // 4*H
constexpr int TD = 63;            // decode steps (T-1)
constexpr int KOUT = 1280;        // 2H + E
constexpr float SQRTE = 16.0f;    // sqrt(256)

DEV float sigf(float x) { return 1.0f / (1.0f + __expf(-x)); }
DEV float tanh_fast(float x) {
    float ax = fabsf(x);
    float t = __expf(-2.f * ax);
    float r = (1.f - t) / (1.f + t);
    return x < 0.f ? -r : r;
}
// clamped direct form (args bounded ~|3| in scores path; clamp guards inf)
DEV float tanh_c(float x) {
    float xc = fminf(fmaxf(x, -15.f), 15.f);
    float t = __expf(2.f * xc);
    return (t - 1.f) / (t + 1.f);
}

// ---------------- device-scope sense barrier ----------------
DEV void gbar(unsigned* cnt, unsigned* gen, unsigned nblk) {
    __syncthreads();
    if (threadIdx.x == 0) {
        __threadfence();   // release all prior global writes (agent scope)
        unsigned g = __hip_atomic_load(gen, __ATOMIC_RELAXED, __HIP_MEMORY_SCOPE_AGENT);
        unsigned old = __hip_atomic_fetch_add(cnt, 1u, __ATOMIC_ACQ_REL, __HIP_MEMORY_SCOPE_AGENT);
        if (old == nblk - 1u) {
            __hip_atomic_store(cnt, 0u, __ATOMIC_RELAXED, __HIP_MEMORY_SCOPE_AGENT);
            __hip_atomic_fetch_add(gen, 1u, __ATOMIC_ACQ_REL, __HIP_MEMORY_SCOPE_AGENT);
        } else {
            unsigned cg;
            do {
                __builtin_amdgcn_s_sleep(2);
                cg = __hip_atomic_load(gen, __ATOMIC_ACQUIRE, __HIP_MEMORY_SCOPE_AGENT);
            } while (cg == g);
        }
        __threadfence();
    }
    __syncthreads();
}

// ============ embeddings (bf16 out) ============
__global__ __launch_bounds__(256) void k_embed_src(const int* __restrict__ tok,
                                                   const float* __restrict__ emb,
                                                   __hip_bfloat16* __restrict__ x)
{
    int idx = blockIdx.x * 256 + threadIdx.x;
    int e = idx & (Eq - 1);
    int r = idx >> 8;
    int b = r & 31, t = r >> 5;
    x[idx] = __float2bfloat16(emb[(size_t)tok[b * Sq + t] * Eq + e] * SQRTE);
}

__global__ __launch_bounds__(256) void k_embed_tgt(const int* __restrict__ tok,
                                                   const float* __restrict__ emb,
                                                   __hip_bfloat16* __restrict__ embt,
                                                   __hip_bfloat16* __restrict__ Xout)
{
    int idx = blockIdx.x * 256 + threadIdx.x;
    int e = idx & (Eq - 1);
    int r = idx >> 8;
    int b = r & 31, t = r >> 5;
    float v = fmaxf(0.f, emb[(size_t)tok[b * Tq + t] * Eq + e] * SQRTE);
    embt[idx] = __float2bfloat16(v);
    Xout[(size_t)r * KOUT + 1024 + e] = __float2bfloat16(v);
}

// ============ transpose + cast W (K x N) -> Wt (N x K) bf16 ============
__global__ __launch_bounds__(256) void k_transpose_bf16(const float* __restrict__ W,
                                                        __hip_bfloat16* __restrict__ Wt,
                                                        int K, int N)
{
    __shared__ float tile[32][33];
    int nb = blockIdx.x * 32, kb = blockIdx.y * 32;
    int c = threadIdx.x & 31, r4 = threadIdx.x >> 5;
    for (int i = 0; i < 32; i += 8)
        tile[r4 + i][c] = W[(size_t)(kb + r4 + i) * N + nb + c];
    __syncthreads();
    for (int i = 0; i < 32; i += 8) {
        int rr = r4 + i;
        Wt[(size_t)(nb + rr) * K + kb + c] = __float2bfloat16(tile[c][rr]);
    }
}

// ============ MFMA helpers (recurrent path, K=512, A=32x512) ============
DEV void stage_A(const __hip_bfloat16* A, __bf16* As) {
    int tx = threadIdx.x;
#pragma unroll
    for (int p = 0; p < 8; ++p) {
        int c = tx + p * 256;
        int row = c >> 6, kc = c & 63;
        uint4 v = *(const uint4*)((const unsigned short*)A + row * 512 + kc * 8);
        int kd = kc ^ (row & 7);
        *(uint4*)(As + row * 512 + kd * 8) = v;
    }
}

DEV void mfma_pass(const __bf16* As, const unsigned short* BT, int colB,
                   int kg, int fr, f32x4* acc) {
    const unsigned short* bp = BT + (size_t)colB * 512 + kg * 8;
    int f7 = fr & 7;
#pragma unroll
    for (int k0 = 0; k0 < 512; k0 += 32) {
        int cidx = ((k0 >> 3) | kg) ^ f7;
        bf16x8 bfv = *(const bf16x8*)(bp + k0);
        bf16x8 af0 = *(const bf16x8*)(As + fr * 512 + cidx * 8);
        bf16x8 af1 = *(const bf16x8*)(As + (16 + fr) * 512 + cidx * 8);
        acc[0] = __builtin_amdgcn_mfma_f32_16x16x32_bf16(af0, bfv, acc[0], 0, 0, 0);
        acc[1] = __builtin_amdgcn_mfma_f32_16x16x32_bf16(af1, bfv, acc[1], 0, 0, 0);
    }
}

// MFMA + cell update assuming As0 (and As1 if dual) already staged & synced.
DEV void rec_compute(const __hip_bfloat16* B0T, const __hip_bfloat16* B1T,
                     const __hip_bfloat16* xpart, const float* bias,
                     float* cbuf, float* hf, __hip_bfloat16* hb,
                     float* ef32, int ef32s, __hip_bfloat16* ebf16, int ebs,
                     int j0, __bf16* As0, __bf16* As1)
{
    int tx = threadIdx.x, w = tx >> 6, lane = tx & 63;
    int fr = lane & 15, kg = lane >> 4;
    int colB = w * 512 + j0 + fr;

    f32x4 acc[2];
    acc[0] = (f32x4){0.f, 0.f, 0.f, 0.f};
    acc[1] = (f32x4){0.f, 0.f, 0.f, 0.f};
    mfma_pass(As0, (const unsigned short*)B0T, colB, kg, fr, acc);
    if (B1T) mfma_pass(As1, (const unsigned short*)B1T, colB, kg, fr, acc);

    __syncthreads();                 // LDS reads done; alias As0 as gbuf
    float* gbuf = (float*)As0;       // [4][32][16]
    float* gw = gbuf + w * 512;
#pragma unroll
    for (int m = 0; m < 2; ++m)
#pragma unroll
        for (int q = 0; q < 4; ++q)
            gw[(m * 16 + kg * 4 + q) * 16 + fr] = acc[m][q];
    __syncthreads();

    int idx = tx;
#pragma unroll
    for (int r = 0; r < 2; ++r, idx += 256) {
        int b = idx >> 4, jj = idx & 15, j = j0 + jj;
        float gi = gbuf[0 * 512 + b * 16 + jj];
        float gf = gbuf[1 * 512 + b * 16 + jj];
        float gg = gbuf[2 * 512 + b * 16 + jj];
        float go = gbuf[3 * 512 + b * 16 + jj];
        if (xpart) {
            gi += __bfloat162float(xpart[b * 2048 + j]);
            gf += __bfloat162float(xpart[b * 2048 + 512 + j]);
            gg += __bfloat162float(xpart[b * 2048 + 1024 + j]);
            go += __bfloat162float(xpart[b * 2048 + 1536 + j]);
        }
        if (bias) {
            gi += bias[j]; gf += bias[512 + j];
            gg += bias[1024 + j]; go += bias[1536 + j];
        }
        int ci = b * 512 + j;
        float cc = cbuf[ci];
        float cn = sigf(gf) * cc + sigf(gi) * tanh_fast(gg);
        cbuf[ci] = cn;
        float ho = sigf(go) * tanh_fast(cn);
        hf[ci] = ho;
        hb[ci] = __float2bfloat16(ho);
        if (ef32)  ef32[b * ef32s + j] = ho;
        if (ebf16) ebf16[b * ebs + j] = __float2bfloat16(ho);
    }
}

DEV void rec_core(const __hip_bfloat16* A0, const __hip_bfloat16* B0T,
                  const __hip_bfloat16* A1, const __hip_bfloat16* B1T,
                  const __hip_bfloat16* xpart, const float* bias,
                  float* cbuf, float* hf, __hip_bfloat16* hb,
                  float* ef32, int ef32s, __hip_bfloat16* ebf16, int ebs,
                  int j0, __bf16* As0, __bf16* As1)
{
    stage_A(A0, As0);
    if (A1) stage_A(A1, As1);
    __syncthreads();
    rec_compute(B0T, B1T, xpart, bias, cbuf, hf, hb,
                ef32, ef32s, ebf16, ebs, j0, As0, As1);
}

// ============ persistent encoder (grid 64 x 256, 129 iterations) ============
__global__ __launch_bounds__(256) void k_enc_persist(
    const __hip_bfloat16* __restrict__ X0b,
    const __hip_bfloat16* __restrict__ eWhh0T, const __hip_bfloat16* __restrict__ eWih1T,
    const __hip_bfloat16* __restrict__ eWhh1T, const float* __restrict__ eb1,
    __hip_bfloat16* __restrict__ h0b, __hip_bfloat16* __restrict__ h1b,
    float* __restrict__ h0f, float* __restrict__ h1f,
    float* __restrict__ c0, float* __restrict__ c1,
    __hip_bfloat16* __restrict__ ys0b,
    float* __restrict__ encf, __hip_bfloat16* __restrict__ encb,
    unsigned* __restrict__ gb)
{
    __shared__ __align__(16) __bf16 As0[32 * 512];
    __shared__ __align__(16) __bf16 As1[32 * 512];
    bool lay1 = blockIdx.x >= 32;
    int j0 = (blockIdx.x & 31) * 16;
    unsigned* cnt = gb;            // offsets in unsigned: 0 / 16
    unsigned* gen = gb + 16;
    for (int t = 0; t <= 128; ++t) {
        if (!lay1) {
            if (t < 128)
                rec_core(h0b + (t & 1) * 16384, eWhh0T, nullptr, nullptr,
                         X0b + (size_t)t * 32 * 2048, nullptr,
                         c0, h0f, h0b + ((t + 1) & 1) * 16384,
                         nullptr, 0, ys0b + (size_t)t * 16384, 512, j0, As0, As1);
        } else {
            if (t >= 1) {
                int s = t - 1;
                rec_core(ys0b + (size_t)s * 16384, eWih1T,
                         h1b + (s & 1) * 16384, eWhh1T,
                         nullptr, eb1,
                         c1, h1f, h1b + ((s + 1) & 1) * 16384,
                         encf + s * 512, 128 * 512, encb + s * 512, 128 * 512,
                         j0, As0, As1);
            }
        }
        gbar(cnt, gen, 64);
    }
}

// ============ persistent decoder (grid 64 x 256, 63 steps x 4 phases) ============
__global__ __launch_bounds__(256) void k_dec_persist(
    const float* __restrict__ enc_proj, const float* __restrict__ enc_outf,
    const int* __restrict__ src_tok, const float* __restrict__ v_w,
    const __hip_bfloat16* __restrict__ WqT, const float* __restrict__ attn_b,
    const float* __restrict__ coal_w, const float* __restrict__ coal_b,
    const __hip_bfloat16* __restrict__ dWih0wT, const __hip_bfloat16* __restrict__ dWhh0T,
    const __hip_bfloat16* __restrict__ dWih1T, const __hip_bfloat16* __restrict__ dWhh1T,
    const float* __restrict__ db1, const __hip_bfloat16* __restrict__ Xembb,
    float* __restrict__ h0fd, float* __restrict__ h1fd,
    __hip_bfloat16* __restrict__ h0bd, __hip_bfloat16* __restrict__ h1bd,
    float* __restrict__ c0d, float* __restrict__ c1d,
    float* __restrict__ aq, float* __restrict__ pctx, float* __restrict__ psum,
    __hip_bfloat16* __restrict__ Xout,
    unsigned* __restrict__ gb)
{
    __shared__ __align__(16) __bf16 As0[32 * 512];
    __shared__ __align__(16) __bf16 As1[32 * 512];
    __shared__ float rsum[32];
    int bid = blockIdx.x, tx = threadIdx.x;
    unsigned* cnt = gb + 32;
    unsigned* gen = gb + 48;

    for (int t = 0; t < TD; ++t) {
        int cur = t & 1, nxt = cur ^ 1;
        const float* h0c = h0fd + cur * 16384;
        const float* h1c = h1fd + cur * 16384;
        __hip_bfloat16* XoutT = Xout + (size_t)t * 32 * KOUT;

        // ---- Phase A: aq = relu(coal(h)) @ Wq + attn_b  (blocks 0..7) ----
        if (bid < 8) {
            __bf16* Qs = As0;
            float cw0 = coal_w[0], cw1 = coal_w[1], cb = coal_b[0];
            for (int idx = tx; idx < 16384; idx += 256) {
                int b2 = idx >> 9, j = idx & 511;
                int p = b2 * 1024 + 2 * j;
                float v0 = (p < 16384) ? h0c[p] : h1c[p - 16384];
                float v1 = (p + 1 < 16384) ? h0c[p + 1] : h1c[p + 1 - 16384];
                float q = fmaxf(0.f, v0 * cw0 + v1 * cw1 + cb);
                int kc = j >> 3, kd = kc ^ (b2 & 7);
                Qs[b2 * 512 + kd * 8 + (j & 7)] = __float2bfloat16(q);
            }
            __syncthreads();
            int w = tx >> 6, lane = tx & 63, fr = lane & 15, kg = lane >> 4;
            int col = bid * 64 + w * 16 + fr;
            f32x4 acc[2];
            acc[0] = (f32x4){0.f, 0.f, 0.f, 0.f};
            acc[1] = (f32x4){0.f, 0.f, 0.f, 0.f};
            mfma_pass(Qs, (const unsigned short*)WqT, col, kg, fr, acc);
            float ab = attn_b[col];
#pragma unroll
            for (int m = 0; m < 2; ++m)
#pragma unroll
                for (int q = 0; q < 4; ++q)
                    aq[(m * 16 + kg * 4 + q) * 512 + col] = acc[m][q] + ab;
        }
        gbar(cnt, gen, 64);

        // ---- Phase B: scores -> exp weights -> partial ctx (all 64 blocks) ----
        {
            int b = bid & 31, half = bid >> 5;
            float* aqs = (float*)As0;          // 512
            float* vws = aqs + 512;            // 512
            float* ws  = vws + 512;            // 64
            for (int i = tx; i < 512; i += 256) {
                aqs[i] = aq[b * 512 + i];
                vws[i] = v_w[i];
            }
            __syncthreads();
            int sl = tx >> 2, lq = tx & 3;     // 4 lanes per s, 64 s per block
            int s = half * 64 + sl;
            const float* ep = enc_proj + ((size_t)(b * 128 + s)) * 512 + lq * 128;
            float a0 = 0.f, a1 = 0.f, a2 = 0.f, a3 = 0.f;
#pragma unroll 8
            for (int ii = 0; ii < 128; ii += 4) {
                float4 f = *(const float4*)(ep + ii);
                int ib = lq * 128 + ii;
                a0 += tanh_c(f.x + aqs[ib])     * vws[ib];
                a1 += tanh_c(f.y + aqs[ib + 1]) * vws[ib + 1];
                a2 += tanh_c(f.z + aqs[ib + 2]) * vws[ib + 2];
                a3 += tanh_c(f.w + aqs[ib + 3]) * vws[ib + 3];
            }
            float p = (a0 + a1) + (a2 + a3);
            p += __shfl_xor(p, 1, 64);
            p += __shfl_xor(p, 2, 64);
            if (lq == 0)
                ws[sl] = (src_tok[b * 128 + s] != 1) ? __expf(p) : 0.f;
            __syncthreads();
            // partial (unnormalized) context over this half's 64 s
            float acc0 = 0.f, acc1 = 0.f;
            const float* eo = enc_outf + ((size_t)b * 128 + half * 64) * 512;
#pragma unroll 4
            for (int s2 = 0; s2 < 64; ++s2) {
                float wv = ws[s2];
                acc0 += wv * eo[(size_t)s2 * 512 + tx];
                acc1 += wv * eo[(size_t)s2 * 512 + tx + 256];
            }
            pctx[(size_t)(b * 2 + half) * 512 + tx] = acc0;
            pctx[(size_t)(b * 2 + half) * 512 + tx + 256] = acc1;
            if (tx < 64) {
                float ss = ws[tx];
#pragma unroll
                for (int o = 32; o > 0; o >>= 1) ss += __shfl_down(ss, o, 64);
                if (tx == 0) psum[b * 2 + half] = ss;
            }
        }
        gbar(cnt, gen, 64);

        // ---- Phase D: wctx combine + cell0 (blocks 0..31) ----
        if (bid < 32) {
            int j0 = bid * 16;
            if (tx < 32) rsum[tx] = 1.0f / (psum[tx * 2] + psum[tx * 2 + 1]);
            __syncthreads();
            for (int idx = tx; idx < 16384; idx += 256) {
                int b2 = idx >> 9, i = idx & 511;
                float wv = (pctx[(size_t)(b2 * 2) * 512 + i] +
                            pctx[(size_t)(b2 * 2 + 1) * 512 + i]) * rsum[b2];
                int kc = i >> 3, kd = kc ^ (b2 & 7);
                As0[b2 * 512 + kd * 8 + (i & 7)] = __float2bfloat16(wv);
                if (bid == 0)
                    XoutT[(size_t)b2 * KOUT + 512 + i] = __float2bfloat16(wv);
            }
            stage_A(h0bd + cur * 16384, As1);
            __syncthreads();
            rec_compute(dWih0wT, dWhh0T,
                        Xembb + (size_t)t * 32 * 2048, nullptr,
                        c0d, h0fd + nxt * 16384, h0bd + nxt * 16384,
                        nullptr, 0, nullptr, 0, j0, As0, As1);
        }
        gbar(cnt, gen, 64);

        // ---- Phase E: cell1 (blocks 0..31) ----
        if (bid < 32) {
            int j0 = bid * 16;
            rec_core(h0bd + nxt * 16384, dWih1T,
                     h1bd + cur * 16384, dWhh1T,
                     nullptr, db1,
                     c1d, h1fd + nxt * 16384, h1bd + nxt * 16384,
                     nullptr, 0, XoutT, KOUT, j0, As0, As1);
        }
        gbar(cnt, gen, 64);
    }
}

// ============ generic MFMA GEMM: C(MxN) = A(MxK)bf16 @ BT(NxK)bf16 + bias ============
__global__ __launch_bounds__(256) void k_mfma(
    const __hip_bfloat16* __restrict__ A, const __hip_bfloat16* __restrict__ BT,
    const float* __restrict__ bias, float* __restrict__ Cf,
    __hip_bfloat16* __restrict__ Cb, int M, int N, int K)
{
    __shared__ __bf16 As[128][72];
    __shared__ __bf16 Bs[128][72];
    const unsigned short* Aw = (const unsigned short*)A;
    const unsigned short* Bw = (const unsigned short*)BT;
    int n0 = blockIdx.x * 128, m0 = blockIdx.y * 128;
    int tx = threadIdx.x;
    int w = tx >> 6, lane = tx & 63;
    int wm = (w >> 1) * 64, wn = (w & 1) * 64;
    int fr = lane & 15, kg = lane >> 4;
    f32x4 acc[4][4];
#pragma unroll
    for (int mi = 0; mi < 4; mi++)
#pragma unroll
        for (int ni = 0; ni < 4; ni++) acc[mi][ni] = (f32x4){0.f, 0.f, 0.f, 0.f};

    for (int k0 = 0; k0 < K; k0 += 64) {
        __syncthreads();
#pragma unroll
        for (int p = 0; p < 4; p++) {
            int ch = tx + p * 256;
            int r = ch >> 3, cc = (ch & 7) * 8;
            uint4 va = {0u, 0u, 0u, 0u};
            int m = m0 + r;
            if (m < M) va = *(const uint4*)(Aw + (size_t)m * K + k0 + cc);
            *(uint4*)(&As[r][cc]) = va;
            uint4 vb = *(const uint4*)(Bw + (size_t)(n0 + r) * K + k0 + cc);
            *(uint4*)(&Bs[r][cc]) = vb;
        }
        __syncthreads();
#pragma unroll
        for (int kk = 0; kk < 64; kk += 32) {
            bf16x8 af[4], bfv[4];
#pragma unroll
            for (int i = 0; i < 4; i++) {
                af[i]  = *(const bf16x8*)(&As[wm + i * 16 + fr][kk + kg * 8]);
                bfv[i] = *(const bf16x8*)(&Bs[wn + i * 16 + fr][kk + kg * 8]);
            }
#pragma unroll
            for (int mi = 0; mi < 4; mi++)
#pragma unroll
                for (int ni = 0; ni < 4; ni++)
                    acc[mi][ni] = __builtin_amdgcn_mfma_f32_16x16x32_bf16(
                        af[mi], bfv[ni], acc[mi][ni], 0, 0, 0);
        }
    }
#pragma unroll
    for (int ni = 0; ni < 4; ni++) {
        int n = n0 + wn + ni * 16 + fr;
        float bv = bias ? bias[n] : 0.f;
#pragma unroll
        for (int mi = 0; mi < 4; mi++) {
#pragma unroll
            for (int qd = 0; qd < 4; qd++) {
                int R = m0 + wm + mi * 16 + kg * 4 + qd;
                if (R < M) {
                    float v = acc[mi][ni][qd] + bv;
                    if (Cf) Cf[(size_t)R * N + n] = v;
                    else    Cb[(size_t)R * N + n] = __float2bfloat16(v);
                }
            }
        }
    }
}

// ============ small kernels ============
__global__ __launch_bounds__(256) void k_init_dec(
    const float* __restrict__ h0e, const float* __restrict__ h1e,
    const float* __restrict__ c0e, const float* __restrict__ c1e,
    float* __restrict__ h0fd, float* __restrict__ h1fd,
    __hip_bfloat16* __restrict__ h0bd, __hip_bfloat16* __restrict__ h1bd,
    float* __restrict__ c0d, float* __restrict__ c1d)
{
    int idx = blockIdx.x * 256 + threadIdx.x;
    float a = h0e[idx], b = h1e[idx];
    h0fd[idx] = a; h1fd[idx] = b;
    h0bd[idx] = __float2bfloat16(a);
    h1bd[idx] = __float2bfloat16(b);
    c0d[idx] = c0e[idx];
    c1d[idx] = c1e[idx];
}

__global__ __launch_bounds__(256) void k_bos(float* __restrict__ out)
{
    int b = blockIdx.y;
    int i = blockIdx.x * 256 + threadIdx.x;
    out[(size_t)b * (Tq * Vq) + i] = 2.0f;
}

__global__ __launch_bounds__(256) void k_finalize(
    const float* __restrict__ h0f, const float* __restrict__ h1f,
    const float* __restrict__ c0f, const float* __restrict__ c1f,
    float* __restrict__ out)
{
    int idx = blockIdx.x * 256 + threadIdx.x;
    size_t base = (size_t)Bq * Tq * Vq;
    out[base + idx] = h0f[idx];
    out[base + 16384 + idx] = h1f[idx];
    out[base + 32768 + idx] = c0f[idx];
    out[base + 49152 + idx] = c1f[idx];
}

// ============ logits GEMM (scatter epilogue) ============
__global__ __launch_bounds__(256) void k_logits(
    const __hip_bfloat16* __restrict__ A, const __hip_bfloat16* __restrict__ Bt,
    const float* __restrict__ bias, float* __restrict__ out)
{
    __shared__ __bf16 As[128][72];
    __shared__ __bf16 Bs[128][72];
    const unsigned short* Aw = (const unsigned short*)A;
    const unsigned short* Bw = (const unsigned short*)Bt;
    int n0 = blockIdx.x * 128, m0 = blockIdx.y * 128;
    int tx = threadIdx.x;
    int w = tx >> 6, lane = tx & 63;
    int wm = (w >> 1) * 64, wn = (w & 1) * 64;
    int fr = lane & 15, kg = lane >> 4;
    f32x4 acc[4][4];
#pragma unroll
    for (int mi = 0; mi < 4; mi++)
#pragma unroll
        for (int ni = 0; ni < 4; ni++) acc[mi][ni] = (f32x4){0.f, 0.f, 0.f, 0.f};

    for (int k0 = 0; k0 < 1280; k0 += 64) {
        __syncthreads();
#pragma unroll
        for (int p = 0; p < 4; p++) {
            int ch = tx + p * 256;
            int r = ch >> 3, cc = (ch & 7) * 8;
            uint4 va = {0u, 0u, 0u, 0u};
            int m = m0 + r;
            if (m < 2016) va = *(const uint4*)(Aw + (size_t)m * 1280 + k0 + cc);
            *(uint4*)(&As[r][cc]) = va;
            uint4 vb = *(const uint4*)(Bw + (size_t)(n0 + r) * 1280 + k0 + cc);
            *(uint4*)(&Bs[r][cc]) = vb;
        }
        __syncthreads();
#pragma unroll
        for (int kk = 0; kk < 64; kk += 32) {
            bf16x8 af[4], bfv[4];
#pragma unroll
            for (int i = 0; i < 4; i++) {
                af[i]  = *(const bf16x8*)(&As[wm + i * 16 + fr][kk + kg * 8]);
                bfv[i] = *(const bf16x8*)(&Bs[wn + i * 16 + fr][kk + kg * 8]);
            }
#pragma unroll
            for (int mi = 0; mi < 4; mi++)
#pragma unroll
                for (int ni = 0; ni < 4; ni++)
                    acc[mi][ni] = __builtin_amdgcn_mfma_f32_16x16x32_bf16(
                        af[mi], bfv[ni], acc[mi][ni], 0, 0, 0);
        }
    }
#pragma unroll
    for (int ni = 0; ni < 4; ni++) {
        int n = n0 + wn + ni * 16 + fr;
        float bv = bias[n];
#pragma unroll
        for (int mi = 0; mi < 4; mi++) {
#pragma unroll
            for (int qd = 0; qd < 4; qd++) {
                int R = m0 + wm + mi * 16 + kg * 4 + qd;
                if (R < 2016) {
                    int bb = R & 31, ts = R >> 5;
                    out[(size_t)bb * (Tq * Vq) + (size_t)(ts + 1) * Vq + n] =
                        acc[mi][ni][qd] + bv;
                }
            }
        }
    }
}

// ============ launcher ============
extern "C" void kernel_launch(void* const* d_in, const int* in_sizes, int n_in,
                              void* d_out, int out_size, void* d_ws, size_t ws_size,
                              hipStream_t stream)
{
    (void)in_sizes; (void)n_in; (void)out_size; (void)ws_size;
    const int*   src_tok = (const int*)  d_in[0];
    const int*   tgt_tok = (const int*)  d_in[1];
    const float* src_emb = (const float*)d_in[2];
    const float* tgt_emb = (const float*)d_in[3];
    const float* eWih0   = (const float*)d_in[4];
    const float* eWhh0   = (const float*)d_in[5];
    const float* eb0     = (const float*)d_in[6];
    const float* eWih1   = (const float*)d_in[7];
    const float* eWhh1   = (const float*)d_in[8];
    const float* eb1     = (const float*)d_in[9];
    const float* dWih0   = (const float*)d_in[10];
    const float* dWhh0   = (const float*)d_in[11];
    const float* db0     = (const float*)d_in[12];
    const float* dWih1   = (const float*)d_in[13];
    const float* dWhh1   = (const float*)d_in[14];
    const float* db1     = (const float*)d_in[15];
    const float* attn_W  = (const float*)d_in[16];
    const float* attn_b  = (const float*)d_in[17];
    const float* v_w     = (const float*)d_in[18];
    const float* coal_w  = (const float*)d_in[19];
    const float* coal_b  = (const float*)d_in[20];
    const float* out_W   = (const float*)d_in[21];
    const float* out_b   = (const float*)d_in[22];
    float* out = (float*)d_out;

    char* ws = (char*)d_ws;
    size_t off = 0;
    auto alloc = [&](size_t bytes) -> char* {
        char* p = ws + off;
        off += (bytes + 255) & ~(size_t)255;
        return p;
    };
    typedef __hip_bfloat16 BF;
    BF* X0b     = (BF*)alloc(4096ull * 2048 * 2);
    BF* Xembb   = (BF*)alloc(2016ull * 2048 * 2);
    BF* x_srcb  = (BF*)alloc(4096ull * 256 * 2);
    BF* embtb   = (BF*)alloc(2016ull * 256 * 2);
    BF* ys0b    = (BF*)alloc(128ull * 16384 * 2);
    float* enc_outf = (float*)alloc(4096ull * 512 * 4);
    BF* enc_outb    = (BF*)alloc(4096ull * 512 * 2);
    float* enc_proj = (float*)alloc(4096ull * 512 * 4);
    float* aq       = (float*)alloc(16384ull * 4);
    float* pctx     = (float*)alloc(64ull * 512 * 4);
    float* psum     = (float*)alloc(64ull * 4);
    BF* Xout        = (BF*)alloc(2016ull * 1280 * 2);
    BF* Wt          = (BF*)alloc(32000ull * 1280 * 2);
    BF* eWhh0T  = (BF*)alloc(2048ull * 512 * 2);
    BF* eWih1T  = (BF*)alloc(2048ull * 512 * 2);
    BF* eWhh1T  = (BF*)alloc(2048ull * 512 * 2);
    BF* dWih0wT = (BF*)alloc(2048ull * 512 * 2);
    BF* dWhh0T  = (BF*)alloc(2048ull * 512 * 2);
    BF* dWih1T  = (BF*)alloc(2048ull * 512 * 2);
    BF* dWhh1T  = (BF*)alloc(2048ull * 512 * 2);
    BF* eWih0T  = (BF*)alloc(2048ull * 256 * 2);
    BF* dWih0eT = (BF*)alloc(2048ull * 256 * 2);
    BF* WqT     = (BF*)alloc(512ull * 512 * 2);
    BF* WeT     = (BF*)alloc(512ull * 512 * 2);
    BF* h0b_e   = (BF*)alloc(2ull * 16384 * 2);
    BF* h1b_e   = (BF*)alloc(2ull * 16384 * 2);
    float* h0f_e = (float*)alloc(16384ull * 4);
    float* h1f_e = (float*)alloc(16384ull * 4);
    float* c0e   = (float*)alloc(16384ull * 4);
    float* c1e   = (float*)alloc(16384ull * 4);
    float* h0fd  = (float*)alloc(2ull * 16384 * 4);
    float* h1fd  = (float*)alloc(2ull * 16384 * 4);
    BF* h0bd     = (BF*)alloc(2ull * 16384 * 2);
    BF* h1bd     = (BF*)alloc(2ull * 16384 * 2);
    float* c0d   = (float*)alloc(16384ull * 4);
    float* c1d   = (float*)alloc(16384ull * 4);
    unsigned* gbb = (unsigned*)alloc(256);

    hipMemsetAsync(gbb, 0, 256, stream);
    hipMemsetAsync(h0b_e, 0, 2 * 16384 * 2, stream);
    hipMemsetAsync(h1b_e, 0, 2 * 16384 * 2, stream);
    hipMemsetAsync(c0e, 0, 16384 * 4, stream);
    hipMemsetAsync(c1e, 0, 16384 * 4, stream);

    // embeddings
    k_embed_src<<<4096, 256, 0, stream>>>(src_tok, src_emb, x_srcb);
    k_embed_tgt<<<2016, 256, 0, stream>>>(tgt_tok, tgt_emb, embtb, Xout);

    // weight transposes (f32 -> bf16, N-major)
    k_transpose_bf16<<<dim3(64, 16), 256, 0, stream>>>(eWhh0, eWhh0T, 512, 2048);
    k_transpose_bf16<<<dim3(64, 16), 256, 0, stream>>>(eWih1, eWih1T, 512, 2048);
    k_transpose_bf16<<<dim3(64, 16), 256, 0, stream>>>(eWhh1, eWhh1T, 512, 2048);
    k_transpose_bf16<<<dim3(64, 16), 256, 0, stream>>>(dWih0 + 256 * 2048, dWih0wT, 512, 2048);
    k_transpose_bf16<<<dim3(64, 16), 256, 0, stream>>>(dWhh0, dWhh0T, 512, 2048);
    k_transpose_bf16<<<dim3(64, 16), 256, 0, stream>>>(dWih1, dWih1T, 512, 2048);
    k_transpose_bf16<<<dim3(64, 16), 256, 0, stream>>>(dWhh1, dWhh1T, 512, 2048);
    k_transpose_bf16<<<dim3(64, 8), 256, 0, stream>>>(eWih0, eWih0T, 256, 2048);
    k_transpose_bf16<<<dim3(64, 8), 256, 0, stream>>>(dWih0, dWih0eT, 256, 2048);
    k_transpose_bf16<<<dim3(16, 16), 256, 0, stream>>>(attn_W, WqT, 512, 512);
    k_transpose_bf16<<<dim3(16, 16), 256, 0, stream>>>(attn_W + 512 * 512, WeT, 512, 512);
    k_transpose_bf16<<<dim3(1000, 40), 256, 0, stream>>>(out_W, Wt, 1280, 32000);

    // input-side GEMMs (bf16 out)
    k_mfma<<<dim3(16, 32), 256, 0, stream>>>(x_srcb, eWih0T, eb0, nullptr, X0b, 4096, 2048, 256);
    k_mfma<<<dim3(16, 16), 256, 0, stream>>>(embtb, dWih0eT, db0, nullptr, Xembb, 2016, 2048, 256);
    k_bos<<<dim3(125, 32), 256, 0, stream>>>(out);

    // persistent encoder
    k_enc_persist<<<64, 256, 0, stream>>>(X0b, eWhh0T, eWih1T, eWhh1T, eb1,
                                          h0b_e, h1b_e, h0f_e, h1f_e, c0e, c1e,
                                          ys0b, enc_outf, enc_outb, gbb);

    // enc_proj = enc_out @ We (f32 out)
    k_mfma<<<dim3(4, 32), 256, 0, stream>>>(enc_outb, WeT, nullptr, enc_proj, nullptr, 4096, 512, 512);

    k_init_dec<<<64, 256, 0, stream>>>(h0f_e, h1f_e, c0e, c1e,
                                       h0fd, h1fd, h0bd, h1bd, c0d, c1d);

    // persistent decoder
    k_dec_persist<<<64, 256, 0, stream>>>(enc_proj, enc_outf, src_tok, v_w,
                                          WqT, attn_b, coal_w, coal_b,
                                          dWih0wT, dWhh0T, dWih1T, dWhh1T,
                                          db1, Xembb,
                                          h0fd, h1fd, h0bd, h1bd, c0d, c1d,
                                          aq, pctx, psum, Xout, gbb);

    k_finalize<<<64, 256, 0, stream>>>(h0fd + (TD & 1) * 16384, h1fd + (TD & 1) * 16384,
                                       c0d, c1d, out);
    k_logits<<<dim3(250, 16), 256, 0, stream>>>(Xout, Wt, out_b, out);
}

// Round 4
// 6230.324 us; speedup vs baseline: 1.2698x; 1.2698x over previous
//
#include <hip/hip_runtime.h>
#include <hip/hip_bf16.h>

typedef __bf16 bf16x8 __attribute__((ext_vector_type(8)));
typedef float f32x4 __attribute__((ext_vector_type(4)));
typedef unsigned long long u64;

#define DEV static __device__ __forceinline__

constexpr int Bq = 32, Sq = 128, Tq = 64, Eq = 256, Hq = 512, Vq = 32000;
constexpr int G4 = 2048;          // 4*H
constexpr int TD = 63;            // decode steps (T-1)
constexpr int KOUT = 1280;        // 2H + E
constexpr float SQRTE = 16.0f;    // sqrt(256)

DEV float sigf(float x) { return 1.0f / (1.0f + __expf(-x)); }
DEV float tanh_fast(float x) {
    float ax = fabsf(x);
    float t = __expf(-2.f * ax);
    float r = (1.f - t) / (1.f + t);
    return x < 0.f ? -r : r;
}
DEV float tanh_c(float x) {
    float xc = fminf(fmaxf(x, -15.f), 15.f);
    float t = __expf(2.f * xc);
    return (t - 1.f) / (t + 1.f);
}

// ---- coherent (agent-scope, cache-bypassing) access helpers ----
DEV u64 ldc(const u64* p) {
    return __hip_atomic_load(p, __ATOMIC_RELAXED, __HIP_MEMORY_SCOPE_AGENT);
}
DEV void stc(u64* p, u64 v) {
    __hip_atomic_store(p, v, __ATOMIC_RELAXED, __HIP_MEMORY_SCOPE_AGENT);
}
DEV void stc32(unsigned* p, unsigned v) {
    __hip_atomic_store(p, v, __ATOMIC_RELAXED, __HIP_MEMORY_SCOPE_AGENT);
}
DEV unsigned short bfbits(float f) {
    __bf16 h = (__bf16)f;
    return __builtin_bit_cast(unsigned short, h);
}
DEV float bf2f(unsigned short u) {
    __bf16 h = __builtin_bit_cast(__bf16, u);
    return (float)h;
}
DEV u64 pack4bf(float a, float b, float c, float d) {
    return (u64)bfbits(a) | ((u64)bfbits(b) << 16) |
           ((u64)bfbits(c) << 32) | ((u64)bfbits(d) << 48);
}
DEV u64 pack2f(float a, float b) {
    return (u64)__float_as_uint(a) | ((u64)__float_as_uint(b) << 32);
}

// ---- cache-op-free global barrier: monotonic counter, relaxed atomics only ----
// __syncthreads() drains each wave's vmcnt before s_barrier, so all this
// block's (write-through) stores are complete before arrival.
DEV void gbar(unsigned* cnt, unsigned target) {
    __syncthreads();
    if (threadIdx.x == 0) {
        asm volatile("s_waitcnt vmcnt(0)" ::: "memory");
        __hip_atomic_fetch_add(cnt, 1u, __ATOMIC_RELAXED, __HIP_MEMORY_SCOPE_AGENT);
        while (__hip_atomic_load(cnt, __ATOMIC_RELAXED, __HIP_MEMORY_SCOPE_AGENT) < target)
            __builtin_amdgcn_s_sleep(1);
    }
    __syncthreads();
}

// ============ embeddings (bf16 out) ============
__global__ __launch_bounds__(256) void k_embed_src(const int* __restrict__ tok,
                                                   const float* __restrict__ emb,
                                                   __hip_bfloat16* __restrict__ x)
{
    int idx = blockIdx.x * 256 + threadIdx.x;
    int e = idx & (Eq - 1);
    int r = idx >> 8;
    int b = r & 31, t = r >> 5;
    x[idx] = __float2bfloat16(emb[(size_t)tok[b * Sq + t] * Eq + e] * SQRTE);
}

__global__ __launch_bounds__(256) void k_embed_tgt(const int* __restrict__ tok,
                                                   const float* __restrict__ emb,
                                                   __hip_bfloat16* __restrict__ embt,
                                                   __hip_bfloat16* __restrict__ Xout)
{
    int idx = blockIdx.x * 256 + threadIdx.x;
    int e = idx & (Eq - 1);
    int r = idx >> 8;
    int b = r & 31, t = r >> 5;
    float v = fmaxf(0.f, emb[(size_t)tok[b * Tq + t] * Eq + e] * SQRTE);
    embt[idx] = __float2bfloat16(v);
    Xout[(size_t)r * KOUT + 1024 + e] = __float2bfloat16(v);
}

// ============ transpose + cast W (K x N) -> Wt (N x K) bf16 ============
__global__ __launch_bounds__(256) void k_transpose_bf16(const float* __restrict__ W,
                                                        __hip_bfloat16* __restrict__ Wt,
                                                        int K, int N)
{
    __shared__ float tile[32][33];
    int nb = blockIdx.x * 32, kb = blockIdx.y * 32;
    int c = threadIdx.x & 31, r4 = threadIdx.x >> 5;
    for (int i = 0; i < 32; i += 8)
        tile[r4 + i][c] = W[(size_t)(kb + r4 + i) * N + nb + c];
    __syncthreads();
    for (int i = 0; i < 32; i += 8) {
        int rr = r4 + i;
        Wt[(size_t)(nb + rr) * K + kb + c] = __float2bfloat16(tile[c][rr]);
    }
}

// ============ MFMA recurrent helpers (K=512, A=32x512 in LDS, swizzled) ============
DEV void stage_coh(const u64* src, __bf16* As) {
    int tx = threadIdx.x;
#pragma unroll
    for (int p = 0; p < 8; ++p) {
        int c = tx + p * 256;                  // chunk of 8 bf16
        int row = c >> 6, kc = c & 63;
        u64 v0 = ldc(src + c * 2);
        u64 v1 = ldc(src + c * 2 + 1);
        int kd = kc ^ (row & 7);
        *(u64*)(As + row * 512 + kd * 8) = v0;
        *(u64*)(As + row * 512 + kd * 8 + 4) = v1;
    }
}

DEV void mfma_pass(const __bf16* As, const unsigned short* BT, int colB,
                   int kg, int fr, f32x4* acc) {
    const unsigned short* bp = BT + (size_t)colB * 512 + kg * 8;
    int f7 = fr & 7;
#pragma unroll
    for (int k0 = 0; k0 < 512; k0 += 32) {
        int cidx = ((k0 >> 3) | kg) ^ f7;
        bf16x8 bfv = *(const bf16x8*)(bp + k0);
        bf16x8 af0 = *(const bf16x8*)(As + fr * 512 + cidx * 8);
        bf16x8 af1 = *(const bf16x8*)(As + (16 + fr) * 512 + cidx * 8);
        acc[0] = __builtin_amdgcn_mfma_f32_16x16x32_bf16(af0, bfv, acc[0], 0, 0, 0);
        acc[1] = __builtin_amdgcn_mfma_f32_16x16x32_bf16(af1, bfv, acc[1], 0, 0, 0);
    }
}

// gates GEMM into gbuf (aliases As0 after sync). Waves = gate index.
DEV void mfma_gates(const __bf16* As0, const __bf16* As1,
                    const __hip_bfloat16* B0T, const __hip_bfloat16* B1T,
                    int j0, float* gbuf)
{
    int tx = threadIdx.x, w = tx >> 6, lane = tx & 63;
    int fr = lane & 15, kg = lane >> 4;
    int colB = w * 512 + j0 + fr;
    f32x4 acc[2];
    acc[0] = (f32x4){0.f, 0.f, 0.f, 0.f};
    acc[1] = (f32x4){0.f, 0.f, 0.f, 0.f};
    mfma_pass(As0, (const unsigned short*)B0T, colB, kg, fr, acc);
    if (B1T) mfma_pass(As1, (const unsigned short*)B1T, colB, kg, fr, acc);
    __syncthreads();
    float* gw = gbuf + w * 512;
#pragma unroll
    for (int m = 0; m < 2; ++m)
#pragma unroll
        for (int qd = 0; qd < 4; ++qd)
            gw[(m * 16 + kg * 4 + qd) * 16 + fr] = acc[m][qd];
    __syncthreads();
}

// cell update epilogue: coherent h stores (bf16 + f32), private c, optional extra out.
DEV void cell_epi(const float* gbuf, const __hip_bfloat16* xpart, const float* bias,
                  float* cbuf, u64* hb, u64* hf,
                  __hip_bfloat16* eb, int ebs, bool ebcoh,
                  float* ef, int efs, int j0)
{
    int tx = threadIdx.x;
    if (tx >= 128) return;
    int b = tx >> 2, jg = tx & 3;
    int jj0 = jg * 4;
    int j = j0 + jj0;
    float g[4][4];
#pragma unroll
    for (int gi = 0; gi < 4; ++gi) {
        float4 gv = *(const float4*)(gbuf + gi * 512 + b * 16 + jj0);
        g[gi][0] = gv.x; g[gi][1] = gv.y; g[gi][2] = gv.z; g[gi][3] = gv.w;
        if (xpart) {
            u64 xv = *(const u64*)((const unsigned short*)xpart + b * 2048 + gi * 512 + j);
#pragma unroll
            for (int e = 0; e < 4; ++e)
                g[gi][e] += bf2f((unsigned short)(xv >> (16 * e)));
        }
        if (bias) {
            float4 bv = *(const float4*)(bias + gi * 512 + j);
            g[gi][0] += bv.x; g[gi][1] += bv.y; g[gi][2] += bv.z; g[gi][3] += bv.w;
        }
    }
    float4 cv = *(float4*)(cbuf + b * 512 + j);
    float cc[4] = {cv.x, cv.y, cv.z, cv.w};
    float hv[4];
#pragma unroll
    for (int e = 0; e < 4; ++e) {
        float cn = sigf(g[1][e]) * cc[e] + sigf(g[0][e]) * tanh_fast(g[2][e]);
        cc[e] = cn;
        hv[e] = sigf(g[3][e]) * tanh_fast(cn);
    }
    *(float4*)(cbuf + b * 512 + j) = make_float4(cc[0], cc[1], cc[2], cc[3]);
    u64 hpk = pack4bf(hv[0], hv[1], hv[2], hv[3]);
    stc(hb + ((b * 512 + j) >> 2), hpk);
    stc(hf + ((b * 512 + j) >> 1), pack2f(hv[0], hv[1]));
    stc(hf + ((b * 512 + j) >> 1) + 1, pack2f(hv[2], hv[3]));
    if (eb) {
        if (ebcoh) stc((u64*)(eb + (size_t)b * ebs + j), hpk);
        else       *(u64*)(eb + (size_t)b * ebs + j) = hpk;
    }
    if (ef) *(float4*)(ef + (size_t)b * efs + j) = make_float4(hv[0], hv[1], hv[2], hv[3]);
}

// ============ persistent encoder (64 blocks: 0-31 layer0 @t, 32-63 layer1 @t-1) ============
__global__ __launch_bounds__(256) void k_enc_persist(
    const __hip_bfloat16* __restrict__ X0b,
    const __hip_bfloat16* __restrict__ eWhh0T, const __hip_bfloat16* __restrict__ eWih1T,
    const __hip_bfloat16* __restrict__ eWhh1T, const float* __restrict__ eb1,
    __hip_bfloat16* __restrict__ h0b, __hip_bfloat16* __restrict__ h1b,
    float* __restrict__ h0f, float* __restrict__ h1f,
    float* __restrict__ c0, float* __restrict__ c1,
    __hip_bfloat16* __restrict__ ys0b,
    float* __restrict__ encf, __hip_bfloat16* __restrict__ encb,
    unsigned* __restrict__ gb)
{
    __shared__ __align__(16) char shm[65536];
    __bf16* As0 = (__bf16*)shm;
    __bf16* As1 = (__bf16*)(shm + 32768);
    bool lay1 = blockIdx.x >= 32;
    int j0 = (blockIdx.x & 31) * 16;
    unsigned* cnt = gb;
    for (int t = 0; t <= 128; ++t) {
        if (!lay1) {
            if (t < 128) {
                stage_coh((const u64*)(h0b + (t & 1) * 16384), As0);
                __syncthreads();
                mfma_gates(As0, nullptr, eWhh0T, nullptr, j0, (float*)As0);
                cell_epi((float*)As0, X0b + (size_t)t * 32 * 2048, nullptr,
                         c0, (u64*)(h0b + ((t + 1) & 1) * 16384), (u64*)h0f,
                         ys0b + (size_t)t * 16384, 512, true, nullptr, 0, j0);
            }
        } else {
            if (t >= 1) {
                int s = t - 1;
                stage_coh((const u64*)(ys0b + (size_t)s * 16384), As0);
                stage_coh((const u64*)(h1b + (s & 1) * 16384), As1);
                __syncthreads();
                mfma_gates(As0, As1, eWih1T, eWhh1T, j0, (float*)As0);
                cell_epi((float*)As0, nullptr, eb1,
                         c1, (u64*)(h1b + ((s + 1) & 1) * 16384), (u64*)h1f,
                         encb + s * 512, 128 * 512, false,
                         encf + s * 512, 128 * 512, j0);
            }
        }
        gbar(cnt, 64u * (unsigned)(t + 1));
    }
}

// ============ persistent decoder (32 blocks, 63 steps x 3 phases) ============
__global__ __launch_bounds__(256) void k_dec_persist(
    const float* __restrict__ enc_proj, const float* __restrict__ enc_outf,
    const int* __restrict__ src_tok, const float* __restrict__ v_w,
    const __hip_bfloat16* __restrict__ WqT, const float* __restrict__ attn_b,
    const float* __restrict__ coal_w, const float* __restrict__ coal_b,
    const __hip_bfloat16* __restrict__ dWih0wT, const __hip_bfloat16* __restrict__ dWhh0T,
    const __hip_bfloat16* __restrict__ dWih1T, const __hip_bfloat16* __restrict__ dWhh1T,
    const float* __restrict__ db1, const __hip_bfloat16* __restrict__ Xembb,
    float* __restrict__ h0fd, float* __restrict__ h1fd,
    __hip_bfloat16* __restrict__ h0bd, __hip_bfloat16* __restrict__ h1bd,
    float* __restrict__ c0d, float* __restrict__ c1d,
    __hip_bfloat16* __restrict__ wctxb,
    __hip_bfloat16* __restrict__ Xout,
    unsigned* __restrict__ gb)
{
    __shared__ __align__(16) char shm[65536];
    __shared__ float rinvs;
    __bf16* As0 = (__bf16*)shm;
    __bf16* As1 = (__bf16*)(shm + 32768);
    int bid = blockIdx.x, tx = threadIdx.x;
    unsigned* cnt = gb + 32;
    unsigned bep = 0;

    for (int t = 0; t < TD; ++t) {
        int cur = t & 1, nxt = cur ^ 1;
        __hip_bfloat16* XoutT = Xout + (size_t)t * 32 * KOUT;

        // ---- Phase B: full attention for batch row b = bid ----
        {
            int b = bid;
            float* q   = (float*)shm;          // 512
            float* aqs = q + 512;              // 512
            float* vws = aqs + 512;            // 512
            float* ws  = vws + 512;            // 128
            const float* hrow = (b < 16) ? (h0fd + cur * 16384 + b * 1024)
                                         : (h1fd + cur * 16384 + (b - 16) * 1024);
            float cw0 = coal_w[0], cw1 = coal_w[1], cb = coal_b[0];
            for (int j = tx; j < 512; j += 256) {
                u64 pv = ldc((const u64*)hrow + j);
                float v0 = __uint_as_float((unsigned)(pv & 0xffffffffu));
                float v1 = __uint_as_float((unsigned)(pv >> 32));
                q[j] = fmaxf(0.f, v0 * cw0 + v1 * cw1 + cb);
            }
            for (int i = tx; i < 512; i += 256) vws[i] = v_w[i];
            __syncthreads();
            // aq[i] = attn_b[i] + sum_j q[j] * Wq[j][i]   (WqT is i-major bf16)
            float a0 = attn_b[tx], a1 = attn_b[tx + 256];
            const unsigned short* w0 = (const unsigned short*)WqT + (size_t)tx * 512;
            const unsigned short* w1 = w0 + 256 * 512;
#pragma unroll 4
            for (int j8 = 0; j8 < 512; j8 += 8) {
                bf16x8 wa = *(const bf16x8*)(w0 + j8);
                bf16x8 wb = *(const bf16x8*)(w1 + j8);
#pragma unroll
                for (int e = 0; e < 8; ++e) {
                    float qe = q[j8 + e];
                    a0 += qe * (float)wa[e];
                    a1 += qe * (float)wb[e];
                }
            }
            aqs[tx] = a0; aqs[tx + 256] = a1;
            __syncthreads();
            // scores: 2 lanes per s
            int s = tx >> 1, half = tx & 1;
            const float* epr = enc_proj + ((size_t)(b * 128 + s)) * 512 + half * 256;
            float s0 = 0.f, s1 = 0.f, s2 = 0.f, s3 = 0.f;
#pragma unroll 8
            for (int ii = 0; ii < 256; ii += 4) {
                float4 f = *(const float4*)(epr + ii);
                int ib = half * 256 + ii;
                s0 += tanh_c(f.x + aqs[ib])     * vws[ib];
                s1 += tanh_c(f.y + aqs[ib + 1]) * vws[ib + 1];
                s2 += tanh_c(f.z + aqs[ib + 2]) * vws[ib + 2];
                s3 += tanh_c(f.w + aqs[ib + 3]) * vws[ib + 3];
            }
            float p = (s0 + s1) + (s2 + s3);
            p += __shfl_xor(p, 1, 64);
            if (half == 0)
                ws[s] = (src_tok[b * 128 + s] != 1) ? __expf(p) : 0.f;
            __syncthreads();
            if (tx < 64) {
                float ss = ws[tx] + ws[tx + 64];
#pragma unroll
                for (int o = 32; o > 0; o >>= 1) ss += __shfl_down(ss, o, 64);
                if (tx == 0) rinvs = 1.0f / ss;
            }
            __syncthreads();
            float rinv = rinvs;
            // ctx: thread handles i0 = 2*tx, 2*tx+1
            const float* eo = enc_outf + (size_t)b * 65536;
            int i0 = tx * 2;
            float c0a = 0.f, c1a = 0.f;
#pragma unroll 4
            for (int s2i = 0; s2i < 128; ++s2i) {
                float2 f = *(const float2*)(eo + (size_t)s2i * 512 + i0);
                float wv = ws[s2i];
                c0a += wv * f.x;
                c1a += wv * f.y;
            }
            c0a *= rinv; c1a *= rinv;
            unsigned pk = (unsigned)bfbits(c0a) | ((unsigned)bfbits(c1a) << 16);
            stc32((unsigned*)wctxb + ((b * 512 + i0) >> 1), pk);
            *((unsigned*)XoutT + (((size_t)b * KOUT + 512 + i0) >> 1)) = pk;
        }
        gbar(cnt, 32u * (++bep));

        // ---- Phase D: cell0 ----
        {
            int j0 = bid * 16;
            stage_coh((const u64*)wctxb, As0);
            stage_coh((const u64*)(h0bd + cur * 16384), As1);
            __syncthreads();
            mfma_gates(As0, As1, dWih0wT, dWhh0T, j0, (float*)As0);
            cell_epi((float*)As0, Xembb + (size_t)t * 32 * 2048, nullptr,
                     c0d, (u64*)(h0bd + nxt * 16384), (u64*)(h0fd + nxt * 16384),
                     nullptr, 0, false, nullptr, 0, j0);
        }
        gbar(cnt, 32u * (++bep));

        // ---- Phase E: cell1 ----
        {
            int j0 = bid * 16;
            stage_coh((const u64*)(h0bd + nxt * 16384), As0);
            stage_coh((const u64*)(h1bd + cur * 16384), As1);
            __syncthreads();
            mfma_gates(As0, As1, dWih1T, dWhh1T, j0, (float*)As0);
            cell_epi((float*)As0, nullptr, db1,
                     c1d, (u64*)(h1bd + nxt * 16384), (u64*)(h1fd + nxt * 16384),
                     XoutT, KOUT, false, nullptr, 0, j0);
        }
        gbar(cnt, 32u * (++bep));
    }
}

// ============ generic MFMA GEMM: C(MxN) = A(MxK)bf16 @ BT(NxK)bf16 + bias ============
__global__ __launch_bounds__(256) void k_mfma(
    const __hip_bfloat16* __restrict__ A, const __hip_bfloat16* __restrict__ BT,
    const float* __restrict__ bias, float* __restrict__ Cf,
    __hip_bfloat16* __restrict__ Cb, int M, int N, int K)
{
    __shared__ __bf16 As[128][72];
    __shared__ __bf16 Bs[128][72];
    const unsigned short* Aw = (const unsigned short*)A;
    const unsigned short* Bw = (const unsigned short*)BT;
    int n0 = blockIdx.x * 128, m0 = blockIdx.y * 128;
    int tx = threadIdx.x;
    int w = tx >> 6, lane = tx & 63;
    int wm = (w >> 1) * 64, wn = (w & 1) * 64;
    int fr = lane & 15, kg = lane >> 4;
    f32x4 acc[4][4];
#pragma unroll
    for (int mi = 0; mi < 4; mi++)
#pragma unroll
        for (int ni = 0; ni < 4; ni++) acc[mi][ni] = (f32x4){0.f, 0.f, 0.f, 0.f};

    for (int k0 = 0; k0 < K; k0 += 64) {
        __syncthreads();
#pragma unroll
        for (int p = 0; p < 4; p++) {
            int ch = tx + p * 256;
            int r = ch >> 3, cc = (ch & 7) * 8;
            uint4 va = {0u, 0u, 0u, 0u};
            int m = m0 + r;
            if (m < M) va = *(const uint4*)(Aw + (size_t)m * K + k0 + cc);
            *(uint4*)(&As[r][cc]) = va;
            uint4 vb = *(const uint4*)(Bw + (size_t)(n0 + r) * K + k0 + cc);
            *(uint4*)(&Bs[r][cc]) = vb;
        }
        __syncthreads();
#pragma unroll
        for (int kk = 0; kk < 64; kk += 32) {
            bf16x8 af[4], bfv[4];
#pragma unroll
            for (int i = 0; i < 4; i++) {
                af[i]  = *(const bf16x8*)(&As[wm + i * 16 + fr][kk + kg * 8]);
                bfv[i] = *(const bf16x8*)(&Bs[wn + i * 16 + fr][kk + kg * 8]);
            }
#pragma unroll
            for (int mi = 0; mi < 4; mi++)
#pragma unroll
                for (int ni = 0; ni < 4; ni++)
                    acc[mi][ni] = __builtin_amdgcn_mfma_f32_16x16x32_bf16(
                        af[mi], bfv[ni], acc[mi][ni], 0, 0, 0);
        }
    }
#pragma unroll
    for (int ni = 0; ni < 4; ni++) {
        int n = n0 + wn + ni * 16 + fr;
        float bv = bias ? bias[n] : 0.f;
#pragma unroll
        for (int mi = 0; mi < 4; mi++) {
#pragma unroll
            for (int qd = 0; qd < 4; qd++) {
                int R = m0 + wm + mi * 16 + kg * 4 + qd;
                if (R < M) {
                    float v = acc[mi][ni][qd] + bv;
                    if (Cf) Cf[(size_t)R * N + n] = v;
                    else    Cb[(size_t)R * N + n] = __float2bfloat16(v);
                }
            }
        }
    }
}

// ============ small kernels ============
__global__ __launch_bounds__(256) void k_init_dec(
    const float* __restrict__ h0e, const float* __restrict__ h1e,
    const float* __restrict__ c0e, const float* __restrict__ c1e,
    float* __restrict__ h0fd, float* __restrict__ h1fd,
    __hip_bfloat16* __restrict__ h0bd, __hip_bfloat16* __restrict__ h1bd,
    float* __restrict__ c0d, float* __restrict__ c1d)
{
    int idx = blockIdx.x * 256 + threadIdx.x;
    float a = h0e[idx], b = h1e[idx];
    h0fd[idx] = a; h1fd[idx] = b;
    h0bd[idx] = __float2bfloat16(a);
    h1bd[idx] = __float2bfloat16(b);
    c0d[idx] = c0e[idx];
    c1d[idx] = c1e[idx];
}

__global__ __launch_bounds__(256) void k_bos(float* __restrict__ out)
{
    int b = blockIdx.y;
    int i = blockIdx.x * 256 + threadIdx.x;
    out[(size_t)b * (Tq * Vq) + i] = 2.0f;
}

__global__ __launch_bounds__(256) void k_finalize(
    const float* __restrict__ h0f, const float* __restrict__ h1f,
    const float* __restrict__ c0f, const float* __restrict__ c1f,
    float* __restrict__ out)
{
    int idx = blockIdx.x * 256 + threadIdx.x;
    size_t base = (size_t)Bq * Tq * Vq;
    out[base + idx] = h0f[idx];
    out[base + 16384 + idx] = h1f[idx];
    out[base + 32768 + idx] = c0f[idx];
    out[base + 49152 + idx] = c1f[idx];
}

// ============ logits GEMM (scatter epilogue) ============
__global__ __launch_bounds__(256) void k_logits(
    const __hip_bfloat16* __restrict__ A, const __hip_bfloat16* __restrict__ Bt,
    const float* __restrict__ bias, float* __restrict__ out)
{
    __shared__ __bf16 As[128][72];
    __shared__ __bf16 Bs[128][72];
    const unsigned short* Aw = (const unsigned short*)A;
    const unsigned short* Bw = (const unsigned short*)Bt;
    int n0 = blockIdx.x * 128, m0 = blockIdx.y * 128;
    int tx = threadIdx.x;
    int w = tx >> 6, lane = tx & 63;
    int wm = (w >> 1) * 64, wn = (w & 1) * 64;
    int fr = lane & 15, kg = lane >> 4;
    f32x4 acc[4][4];
#pragma unroll
    for (int mi = 0; mi < 4; mi++)
#pragma unroll
        for (int ni = 0; ni < 4; ni++) acc[mi][ni] = (f32x4){0.f, 0.f, 0.f, 0.f};

    for (int k0 = 0; k0 < 1280; k0 += 64) {
        __syncthreads();
#pragma unroll
        for (int p = 0; p < 4; p++) {
            int ch = tx + p * 256;
            int r = ch >> 3, cc = (ch & 7) * 8;
            uint4 va = {0u, 0u, 0u, 0u};
            int m = m0 + r;
            if (m < 2016) va = *(const uint4*)(Aw + (size_t)m * 1280 + k0 + cc);
            *(uint4*)(&As[r][cc]) = va;
            uint4 vb = *(const uint4*)(Bw + (size_t)(n0 + r) * 1280 + k0 + cc);
            *(uint4*)(&Bs[r][cc]) = vb;
        }
        __syncthreads();
#pragma unroll
        for (int kk = 0; kk < 64; kk += 32) {
            bf16x8 af[4], bfv[4];
#pragma unroll
            for (int i = 0; i < 4; i++) {
                af[i]  = *(const bf16x8*)(&As[wm + i * 16 + fr][kk + kg * 8]);
                bfv[i] = *(const bf16x8*)(&Bs[wn + i * 16 + fr][kk + kg * 8]);
            }
#pragma unroll
            for (int mi = 0; mi < 4; mi++)
#pragma unroll
                for (int ni = 0; ni < 4; ni++)
                    acc[mi][ni] = __builtin_amdgcn_mfma_f32_16x16x32_bf16(
                        af[mi], bfv[ni], acc[mi][ni], 0, 0, 0);
        }
    }
#pragma unroll
    for (int ni = 0; ni < 4; ni++) {
        int n = n0 + wn + ni * 16 + fr;
        float bv = bias[n];
#pragma unroll
        for (int mi = 0; mi < 4; mi++) {
#pragma unroll
            for (int qd = 0; qd < 4; qd++) {
                int R = m0 + wm + mi * 16 + kg * 4 + qd;
                if (R < 2016) {
                    int bb = R & 31, ts = R >> 5;
                    out[(size_t)bb * (Tq * Vq) + (size_t)(ts + 1) * Vq + n] =
                        acc[mi][ni][qd] + bv;
                }
            }
        }
    }
}

// ============ launcher ============
extern "C" void kernel_launch(void* const* d_in, const int* in_sizes, int n_in,
                              void* d_out, int out_size, void* d_ws, size_t ws_size,
                              hipStream_t stream)
{
    (void)in_sizes; (void)n_in; (void)out_size; (void)ws_size;
    const int*   src_tok = (const int*)  d_in[0];
    const int*   tgt_tok = (const int*)  d_in[1];
    const float* src_emb = (const float*)d_in[2];
    const float* tgt_emb = (const float*)d_in[3];
    const float* eWih0   = (const float*)d_in[4];
    const float* eWhh0   = (const float*)d_in[5];
    const float* eb0     = (const float*)d_in[6];
    const float* eWih1   = (const float*)d_in[7];
    const float* eWhh1   = (const float*)d_in[8];
    const float* eb1     = (const float*)d_in[9];
    const float* dWih0   = (const float*)d_in[10];
    const float* dWhh0   = (const float*)d_in[11];
    const float* db0     = (const float*)d_in[12];
    const float* dWih1   = (const float*)d_in[13];
    const float* dWhh1   = (const float*)d_in[14];
    const float* db1     = (const float*)d_in[15];
    const float* attn_W  = (const float*)d_in[16];
    const float* attn_b  = (const float*)d_in[17];
    const float* v_w     = (const float*)d_in[18];
    const float* coal_w  = (const float*)d_in[19];
    const float* coal_b  = (const float*)d_in[20];
    const float* out_W   = (const float*)d_in[21];
    const float* out_b   = (const float*)d_in[22];
    float* out = (float*)d_out;

    char* ws = (char*)d_ws;
    size_t off = 0;
    auto alloc = [&](size_t bytes) -> char* {
        char* p = ws + off;
        off += (bytes + 255) & ~(size_t)255;
        return p;
    };
    typedef __hip_bfloat16 BF;
    BF* X0b     = (BF*)alloc(4096ull * 2048 * 2);
    BF* Xembb   = (BF*)alloc(2016ull * 2048 * 2);
    BF* x_srcb  = (BF*)alloc(4096ull * 256 * 2);
    BF* embtb   = (BF*)alloc(2016ull * 256 * 2);
    BF* ys0b    = (BF*)alloc(128ull * 16384 * 2);
    float* enc_outf = (float*)alloc(4096ull * 512 * 4);
    BF* enc_outb    = (BF*)alloc(4096ull * 512 * 2);
    float* enc_proj = (float*)alloc(4096ull * 512 * 4);
    BF* wctxb       = (BF*)alloc(16384ull * 2);
    BF* Xout        = (BF*)alloc(2016ull * 1280 * 2);
    BF* Wt          = (BF*)alloc(32000ull * 1280 * 2);
    BF* eWhh0T  = (BF*)alloc(2048ull * 512 * 2);
    BF* eWih1T  = (BF*)alloc(2048ull * 512 * 2);
    BF* eWhh1T  = (BF*)alloc(2048ull * 512 * 2);
    BF* dWih0wT = (BF*)alloc(2048ull * 512 * 2);
    BF* dWhh0T  = (BF*)alloc(2048ull * 512 * 2);
    BF* dWih1T  = (BF*)alloc(2048ull * 512 * 2);
    BF* dWhh1T  = (BF*)alloc(2048ull * 512 * 2);
    BF* eWih0T  = (BF*)alloc(2048ull * 256 * 2);
    BF* dWih0eT = (BF*)alloc(2048ull * 256 * 2);
    BF* WqT     = (BF*)alloc(512ull * 512 * 2);
    BF* WeT     = (BF*)alloc(512ull * 512 * 2);
    BF* h0b_e   = (BF*)alloc(2ull * 16384 * 2);
    BF* h1b_e   = (BF*)alloc(2ull * 16384 * 2);
    float* h0f_e = (float*)alloc(16384ull * 4);
    float* h1f_e = (float*)alloc(16384ull * 4);
    float* c0e   = (float*)alloc(16384ull * 4);
    float* c1e   = (float*)alloc(16384ull * 4);
    float* h0fd  = (float*)alloc(2ull * 16384 * 4);
    float* h1fd  = (float*)alloc(2ull * 16384 * 4);
    BF* h0bd     = (BF*)alloc(2ull * 16384 * 2);
    BF* h1bd     = (BF*)alloc(2ull * 16384 * 2);
    float* c0d   = (float*)alloc(16384ull * 4);
    float* c1d   = (float*)alloc(16384ull * 4);
    unsigned* gbb = (unsigned*)alloc(256);

    hipMemsetAsync(gbb, 0, 256, stream);
    hipMemsetAsync(h0b_e, 0, 2 * 16384 * 2, stream);
    hipMemsetAsync(h1b_e, 0, 2 * 16384 * 2, stream);
    hipMemsetAsync(c0e, 0, 16384 * 4, stream);
    hipMemsetAsync(c1e, 0, 16384 * 4, stream);

    // embeddings
    k_embed_src<<<4096, 256, 0, stream>>>(src_tok, src_emb, x_srcb);
    k_embed_tgt<<<2016, 256, 0, stream>>>(tgt_tok, tgt_emb, embtb, Xout);

    // weight transposes (f32 -> bf16, N-major)
    k_transpose_bf16<<<dim3(64, 16), 256, 0, stream>>>(eWhh0, eWhh0T, 512, 2048);
    k_transpose_bf16<<<dim3(64, 16), 256, 0, stream>>>(eWih1, eWih1T, 512, 2048);
    k_transpose_bf16<<<dim3(64, 16), 256, 0, stream>>>(eWhh1, eWhh1T, 512, 2048);
    k_transpose_bf16<<<dim3(64, 16), 256, 0, stream>>>(dWih0 + 256 * 2048, dWih0wT, 512, 2048);
    k_transpose_bf16<<<dim3(64, 16), 256, 0, stream>>>(dWhh0, dWhh0T, 512, 2048);
    k_transpose_bf16<<<dim3(64, 16), 256, 0, stream>>>(dWih1, dWih1T, 512, 2048);
    k_transpose_bf16<<<dim3(64, 16), 256, 0, stream>>>(dWhh1, dWhh1T, 512, 2048);
    k_transpose_bf16<<<dim3(64, 8), 256, 0, stream>>>(eWih0, eWih0T, 256, 2048);
    k_transpose_bf16<<<dim3(64, 8), 256, 0, stream>>>(dWih0, dWih0eT, 256, 2048);
    k_transpose_bf16<<<dim3(16, 16), 256, 0, stream>>>(attn_W, WqT, 512, 512);
    k_transpose_bf16<<<dim3(16, 16), 256, 0, stream>>>(attn_W + 512 * 512, WeT, 512, 512);
    k_transpose_bf16<<<dim3(1000, 40), 256, 0, stream>>>(out_W, Wt, 1280, 32000);

    // input-side GEMMs (bf16 out)
    k_mfma<<<dim3(16, 32), 256, 0, stream>>>(x_srcb, eWih0T, eb0, nullptr, X0b, 4096, 2048, 256);
    k_mfma<<<dim3(16, 16), 256, 0, stream>>>(embtb, dWih0eT, db0, nullptr, Xembb, 2016, 2048, 256);
    k_bos<<<dim3(125, 32), 256, 0, stream>>>(out);

    // persistent encoder
    k_enc_persist<<<64, 256, 0, stream>>>(X0b, eWhh0T, eWih1T, eWhh1T, eb1,
                                          h0b_e, h1b_e, h0f_e, h1f_e, c0e, c1e,
                                          ys0b, enc_outf, enc_outb, gbb);

    // enc_proj = enc_out @ We (f32 out)
    k_mfma<<<dim3(4, 32), 256, 0, stream>>>(enc_outb, WeT, nullptr, enc_proj, nullptr, 4096, 512, 512);

    k_init_dec<<<64, 256, 0, stream>>>(h0f_e, h1f_e, c0e, c1e,
                                       h0fd, h1fd, h0bd, h1bd, c0d, c1d);

    // persistent decoder
    k_dec_persist<<<32, 256, 0, stream>>>(enc_proj, enc_outf, src_tok, v_w,
                                          WqT, attn_b, coal_w, coal_b,
                                          dWih0wT, dWhh0T, dWih1T, dWhh1T,
                                          db1, Xembb,
                                          h0fd, h1fd, h0bd, h1bd, c0d, c1d,
                                          wctxb, Xout, gbb);

    k_finalize<<<64, 256, 0, stream>>>(h0fd + (TD & 1) * 16384, h1fd + (TD & 1) * 16384,
                                       c0d, c1d, out);
    k_logits<<<dim3(250, 16), 256, 0, stream>>>(Xout, Wt, out_b, out);
}

// Round 5
// 5854.125 us; speedup vs baseline: 1.3514x; 1.0643x over previous
//
#include <hip/hip_runtime.h>
#include <hip/hip_bf16.h>

typedef __bf16 bf16x8 __attribute__((ext_vector_type(8)));
typedef float f32x4 __attribute__((ext_vector_type(4)));
typedef unsigned long long u64;

#define DEV static __device__ __forceinline__

constexpr int Bq = 32, Sq = 128, Tq = 64, Eq = 256, Hq = 512, Vq = 32000;
constexpr int G4 = 2048;          // 4*H
constexpr int TD = 63;            // decode steps (T-1)
constexpr int KOUT = 1280;        // 2H + E
constexpr float SQRTE = 16.0f;    // sqrt(256)

DEV float sigf(float x) { return 1.0f / (1.0f + __expf(-x)); }
DEV float tanh_fast(float x) {
    float ax = fabsf(x);
    float t = __expf(-2.f * ax);
    float r = (1.f - t) / (1.f + t);
    return x < 0.f ? -r : r;
}
DEV float tanh_c(float x) {
    float xc = fminf(fmaxf(x, -15.f), 15.f);
    float t = __expf(2.f * xc);
    return (t - 1.f) / (t + 1.f);
}

// ---- coherent (agent-scope) access helpers ----
DEV u64 ldc(const u64* p) {
    return __hip_atomic_load(p, __ATOMIC_RELAXED, __HIP_MEMORY_SCOPE_AGENT);
}
DEV void stc(u64* p, u64 v) {
    __hip_atomic_store(p, v, __ATOMIC_RELAXED, __HIP_MEMORY_SCOPE_AGENT);
}
DEV void stc32(unsigned* p, unsigned v) {
    __hip_atomic_store(p, v, __ATOMIC_RELAXED, __HIP_MEMORY_SCOPE_AGENT);
}
DEV unsigned short bfbits(float f) {
    __bf16 h = (__bf16)f;
    return __builtin_bit_cast(unsigned short, h);
}
DEV float bf2f(unsigned short u) {
    __bf16 h = __builtin_bit_cast(__bf16, u);
    return (float)h;
}
DEV u64 pack4bf(float a, float b, float c, float d) {
    return (u64)bfbits(a) | ((u64)bfbits(b) << 16) |
           ((u64)bfbits(c) << 32) | ((u64)bfbits(d) << 48);
}
DEV u64 pack2f(float a, float b) {
    return (u64)__float_as_uint(a) | ((u64)__float_as_uint(b) << 32);
}

// ---- cache-op-free global barrier: monotonic counter, relaxed atomics only ----
DEV void gbar(unsigned* cnt, unsigned target) {
    __syncthreads();
    if (threadIdx.x == 0) {
        asm volatile("s_waitcnt vmcnt(0)" ::: "memory");
        __hip_atomic_fetch_add(cnt, 1u, __ATOMIC_RELAXED, __HIP_MEMORY_SCOPE_AGENT);
        while (__hip_atomic_load(cnt, __ATOMIC_RELAXED, __HIP_MEMORY_SCOPE_AGENT) < target)
            __builtin_amdgcn_s_sleep(1);
    }
    __syncthreads();
}

// ============ embeddings (bf16 out) ============
__global__ __launch_bounds__(256) void k_embed_src(const int* __restrict__ tok,
                                                   const float* __restrict__ emb,
                                                   __hip_bfloat16* __restrict__ x)
{
    int idx = blockIdx.x * 256 + threadIdx.x;
    int e = idx & (Eq - 1);
    int r = idx >> 8;
    int b = r & 31, t = r >> 5;
    x[idx] = __float2bfloat16(emb[(size_t)tok[b * Sq + t] * Eq + e] * SQRTE);
}

__global__ __launch_bounds__(256) void k_embed_tgt(const int* __restrict__ tok,
                                                   const float* __restrict__ emb,
                                                   __hip_bfloat16* __restrict__ embt,
                                                   __hip_bfloat16* __restrict__ Xout)
{
    int idx = blockIdx.x * 256 + threadIdx.x;
    int e = idx & (Eq - 1);
    int r = idx >> 8;
    int b = r & 31, t = r >> 5;
    float v = fmaxf(0.f, emb[(size_t)tok[b * Tq + t] * Eq + e] * SQRTE);
    embt[idx] = __float2bfloat16(v);
    Xout[(size_t)r * KOUT + 1024 + e] = __float2bfloat16(v);
}

// ============ transpose + cast W (K x N) -> Wt (N x K) bf16 ============
__global__ __launch_bounds__(256) void k_transpose_bf16(const float* __restrict__ W,
                                                        __hip_bfloat16* __restrict__ Wt,
                                                        int K, int N)
{
    __shared__ float tile[32][33];
    int nb = blockIdx.x * 32, kb = blockIdx.y * 32;
    int c = threadIdx.x & 31, r4 = threadIdx.x >> 5;
    for (int i = 0; i < 32; i += 8)
        tile[r4 + i][c] = W[(size_t)(kb + r4 + i) * N + nb + c];
    __syncthreads();
    for (int i = 0; i < 32; i += 8) {
        int rr = r4 + i;
        Wt[(size_t)(nb + rr) * K + kb + c] = __float2bfloat16(tile[c][rr]);
    }
}

// ============ MFMA recurrent helpers (K=512, A=32x512 in LDS, swizzled) ============
DEV void stage_coh(const u64* src, __bf16* As) {
    int tx = threadIdx.x;
#pragma unroll
    for (int p = 0; p < 8; ++p) {
        int c = tx + p * 256;
        int row = c >> 6, kc = c & 63;
        u64 v0 = ldc(src + c * 2);
        u64 v1 = ldc(src + c * 2 + 1);
        int kd = kc ^ (row & 7);
        *(u64*)(As + row * 512 + kd * 8) = v0;
        *(u64*)(As + row * 512 + kd * 8 + 4) = v1;
    }
}

DEV void mfma_pass(const __bf16* As, const unsigned short* BT, int colB,
                   int kg, int fr, f32x4* acc) {
    const unsigned short* bp = BT + (size_t)colB * 512 + kg * 8;
    int f7 = fr & 7;
#pragma unroll
    for (int k0 = 0; k0 < 512; k0 += 32) {
        int cidx = ((k0 >> 3) | kg) ^ f7;
        bf16x8 bfv = *(const bf16x8*)(bp + k0);
        bf16x8 af0 = *(const bf16x8*)(As + fr * 512 + cidx * 8);
        bf16x8 af1 = *(const bf16x8*)(As + (16 + fr) * 512 + cidx * 8);
        acc[0] = __builtin_amdgcn_mfma_f32_16x16x32_bf16(af0, bfv, acc[0], 0, 0, 0);
        acc[1] = __builtin_amdgcn_mfma_f32_16x16x32_bf16(af1, bfv, acc[1], 0, 0, 0);
    }
}

DEV void mfma_gates(const __bf16* As0, const __bf16* As1,
                    const __hip_bfloat16* B0T, const __hip_bfloat16* B1T,
                    int j0, float* gbuf)
{
    int tx = threadIdx.x, w = tx >> 6, lane = tx & 63;
    int fr = lane & 15, kg = lane >> 4;
    int colB = w * 512 + j0 + fr;
    f32x4 acc[2];
    acc[0] = (f32x4){0.f, 0.f, 0.f, 0.f};
    acc[1] = (f32x4){0.f, 0.f, 0.f, 0.f};
    mfma_pass(As0, (const unsigned short*)B0T, colB, kg, fr, acc);
    if (B1T) mfma_pass(As1, (const unsigned short*)B1T, colB, kg, fr, acc);
    __syncthreads();
    float* gw = gbuf + w * 512;
#pragma unroll
    for (int m = 0; m < 2; ++m)
#pragma unroll
        for (int qd = 0; qd < 4; ++qd)
            gw[(m * 16 + kg * 4 + qd) * 16 + fr] = acc[m][qd];
    __syncthreads();
}

DEV void cell_epi(const float* gbuf, const __hip_bfloat16* xpart, const float* bias,
                  float* cbuf, u64* hb, u64* hf,
                  __hip_bfloat16* eb, int ebs, bool ebcoh,
                  int j0)
{
    int tx = threadIdx.x;
    if (tx >= 128) return;
    int b = tx >> 2, jg = tx & 3;
    int jj0 = jg * 4;
    int j = j0 + jj0;
    float g[4][4];
#pragma unroll
    for (int gi = 0; gi < 4; ++gi) {
        float4 gv = *(const float4*)(gbuf + gi * 512 + b * 16 + jj0);
        g[gi][0] = gv.x; g[gi][1] = gv.y; g[gi][2] = gv.z; g[gi][3] = gv.w;
        if (xpart) {
            u64 xv = *(const u64*)((const unsigned short*)xpart + b * 2048 + gi * 512 + j);
#pragma unroll
            for (int e = 0; e < 4; ++e)
                g[gi][e] += bf2f((unsigned short)(xv >> (16 * e)));
        }
        if (bias) {
            float4 bv = *(const float4*)(bias + gi * 512 + j);
            g[gi][0] += bv.x; g[gi][1] += bv.y; g[gi][2] += bv.z; g[gi][3] += bv.w;
        }
    }
    float4 cv = *(float4*)(cbuf + b * 512 + j);
    float cc[4] = {cv.x, cv.y, cv.z, cv.w};
    float hv[4];
#pragma unroll
    for (int e = 0; e < 4; ++e) {
        float cn = sigf(g[1][e]) * cc[e] + sigf(g[0][e]) * tanh_fast(g[2][e]);
        cc[e] = cn;
        hv[e] = sigf(g[3][e]) * tanh_fast(cn);
    }
    *(float4*)(cbuf + b * 512 + j) = make_float4(cc[0], cc[1], cc[2], cc[3]);
    u64 hpk = pack4bf(hv[0], hv[1], hv[2], hv[3]);
    stc(hb + ((b * 512 + j) >> 2), hpk);
    stc(hf + ((b * 512 + j) >> 1), pack2f(hv[0], hv[1]));
    stc(hf + ((b * 512 + j) >> 1) + 1, pack2f(hv[2], hv[3]));
    if (eb) {
        if (ebcoh) stc((u64*)(eb + (size_t)b * ebs + j), hpk);
        else       *(u64*)(eb + (size_t)b * ebs + j) = hpk;
    }
}

// ============ persistent encoder (64 blocks: 0-31 layer0 @t, 32-63 layer1 @t-1) ============
__global__ __launch_bounds__(256) void k_enc_persist(
    const __hip_bfloat16* __restrict__ X0b,
    const __hip_bfloat16* __restrict__ eWhh0T, const __hip_bfloat16* __restrict__ eWih1T,
    const __hip_bfloat16* __restrict__ eWhh1T, const float* __restrict__ eb1,
    __hip_bfloat16* __restrict__ h0b, __hip_bfloat16* __restrict__ h1b,
    float* __restrict__ h0f, float* __restrict__ h1f,
    float* __restrict__ c0, float* __restrict__ c1,
    __hip_bfloat16* __restrict__ ys0b,
    __hip_bfloat16* __restrict__ encb,
    unsigned* __restrict__ gb)
{
    __shared__ __align__(16) char shm[65536];
    __bf16* As0 = (__bf16*)shm;
    __bf16* As1 = (__bf16*)(shm + 32768);
    bool lay1 = blockIdx.x >= 32;
    int j0 = (blockIdx.x & 31) * 16;
    unsigned* cnt = gb;
    for (int t = 0; t <= 128; ++t) {
        if (!lay1) {
            if (t < 128) {
                stage_coh((const u64*)(h0b + (t & 1) * 16384), As0);
                __syncthreads();
                mfma_gates(As0, nullptr, eWhh0T, nullptr, j0, (float*)As0);
                cell_epi((float*)As0, X0b + (size_t)t * 32 * 2048, nullptr,
                         c0, (u64*)(h0b + ((t + 1) & 1) * 16384), (u64*)h0f,
                         ys0b + (size_t)t * 16384, 512, true, j0);
            }
        } else {
            if (t >= 1) {
                int s = t - 1;
                stage_coh((const u64*)(ys0b + (size_t)s * 16384), As0);
                stage_coh((const u64*)(h1b + (s & 1) * 16384), As1);
                __syncthreads();
                mfma_gates(As0, As1, eWih1T, eWhh1T, j0, (float*)As0);
                cell_epi((float*)As0, nullptr, eb1,
                         c1, (u64*)(h1b + ((s + 1) & 1) * 16384), (u64*)h1f,
                         encb + s * 512, 128 * 512, false, j0);
            }
        }
        gbar(cnt, 64u * (unsigned)(t + 1));
    }
}

// ============ persistent decoder (32 blocks, 63 steps x 3 phases) ============
// enc_projb / enc_outb are bf16, [b][s][512] — per-XCD slice stays L2-resident.
__global__ __launch_bounds__(256) void k_dec_persist(
    const __hip_bfloat16* __restrict__ enc_projb, const __hip_bfloat16* __restrict__ enc_outb,
    const int* __restrict__ src_tok, const float* __restrict__ v_w,
    const __hip_bfloat16* __restrict__ WqT, const float* __restrict__ attn_b,
    const float* __restrict__ coal_w, const float* __restrict__ coal_b,
    const __hip_bfloat16* __restrict__ dWih0wT, const __hip_bfloat16* __restrict__ dWhh0T,
    const __hip_bfloat16* __restrict__ dWih1T, const __hip_bfloat16* __restrict__ dWhh1T,
    const float* __restrict__ db1, const __hip_bfloat16* __restrict__ Xembb,
    float* __restrict__ h0fd, float* __restrict__ h1fd,
    __hip_bfloat16* __restrict__ h0bd, __hip_bfloat16* __restrict__ h1bd,
    float* __restrict__ c0d, float* __restrict__ c1d,
    __hip_bfloat16* __restrict__ wctxb,
    __hip_bfloat16* __restrict__ Xout,
    unsigned* __restrict__ gb)
{
    __shared__ __align__(16) char shm[65536];
    __shared__ float rinvs;
    __bf16* As0 = (__bf16*)shm;
    __bf16* As1 = (__bf16*)(shm + 32768);
    int bid = blockIdx.x, tx = threadIdx.x;
    unsigned* cnt = gb + 32;
    unsigned bep = 0;

    for (int t = 0; t < TD; ++t) {
        int cur = t & 1, nxt = cur ^ 1;
        __hip_bfloat16* XoutT = Xout + (size_t)t * 32 * KOUT;

        // ---- Phase B: full attention for batch row b = bid ----
        {
            int b = bid;
            float* q   = (float*)shm;          // 512
            float* aqs = q + 512;              // 512
            float* vws = aqs + 512;            // 512
            float* ws  = vws + 512;            // 128
            const float* hrow = (b < 16) ? (h0fd + cur * 16384 + b * 1024)
                                         : (h1fd + cur * 16384 + (b - 16) * 1024);
            float cw0 = coal_w[0], cw1 = coal_w[1], cb = coal_b[0];
            for (int j = tx; j < 512; j += 256) {
                u64 pv = ldc((const u64*)hrow + j);
                float v0 = __uint_as_float((unsigned)(pv & 0xffffffffu));
                float v1 = __uint_as_float((unsigned)(pv >> 32));
                q[j] = fmaxf(0.f, v0 * cw0 + v1 * cw1 + cb);
            }
            for (int i = tx; i < 512; i += 256) vws[i] = v_w[i];
            __syncthreads();
            // aq[i] = attn_b[i] + sum_j q[j] * Wq[j][i]   (WqT is i-major bf16)
            float a0 = attn_b[tx], a1 = attn_b[tx + 256];
            const unsigned short* w0 = (const unsigned short*)WqT + (size_t)tx * 512;
            const unsigned short* w1 = w0 + 256 * 512;
#pragma unroll 4
            for (int j8 = 0; j8 < 512; j8 += 8) {
                bf16x8 wa = *(const bf16x8*)(w0 + j8);
                bf16x8 wb = *(const bf16x8*)(w1 + j8);
#pragma unroll
                for (int e = 0; e < 8; ++e) {
                    float qe = q[j8 + e];
                    a0 += qe * (float)wa[e];
                    a1 += qe * (float)wb[e];
                }
            }
            aqs[tx] = a0; aqs[tx + 256] = a1;
            __syncthreads();
            // scores: 2 lanes per s, bf16 enc_proj
            int s = tx >> 1, half = tx & 1;
            const unsigned short* epr = (const unsigned short*)enc_projb
                                        + ((size_t)(b * 128 + s)) * 512 + half * 256;
            float s0 = 0.f, s1 = 0.f, s2 = 0.f, s3 = 0.f;
#pragma unroll 4
            for (int ii = 0; ii < 256; ii += 8) {
                bf16x8 f8 = *(const bf16x8*)(epr + ii);
                int ib = half * 256 + ii;
                s0 += tanh_c((float)f8[0] + aqs[ib])     * vws[ib];
                s1 += tanh_c((float)f8[1] + aqs[ib + 1]) * vws[ib + 1];
                s2 += tanh_c((float)f8[2] + aqs[ib + 2]) * vws[ib + 2];
                s3 += tanh_c((float)f8[3] + aqs[ib + 3]) * vws[ib + 3];
                s0 += tanh_c((float)f8[4] + aqs[ib + 4]) * vws[ib + 4];
                s1 += tanh_c((float)f8[5] + aqs[ib + 5]) * vws[ib + 5];
                s2 += tanh_c((float)f8[6] + aqs[ib + 6]) * vws[ib + 6];
                s3 += tanh_c((float)f8[7] + aqs[ib + 7]) * vws[ib + 7];
            }
            float p = (s0 + s1) + (s2 + s3);
            p += __shfl_xor(p, 1, 64);
            if (half == 0)
                ws[s] = (src_tok[b * 128 + s] != 1) ? __expf(p) : 0.f;
            __syncthreads();
            if (tx < 64) {
                float ss = ws[tx] + ws[tx + 64];
#pragma unroll
                for (int o = 32; o > 0; o >>= 1) ss += __shfl_down(ss, o, 64);
                if (tx == 0) rinvs = 1.0f / ss;
            }
            __syncthreads();
            float rinv = rinvs;
            // ctx: thread handles i0 = 2*tx, 2*tx+1 (bf16 enc_out)
            const unsigned short* eo = (const unsigned short*)enc_outb + (size_t)b * 65536;
            int i0 = tx * 2;
            float c0a = 0.f, c1a = 0.f;
#pragma unroll 4
            for (int s2i = 0; s2i < 128; ++s2i) {
                unsigned pk2 = *(const unsigned*)(eo + (size_t)s2i * 512 + i0);
                float wv = ws[s2i];
                c0a += wv * bf2f((unsigned short)(pk2 & 0xffffu));
                c1a += wv * bf2f((unsigned short)(pk2 >> 16));
            }
            c0a *= rinv; c1a *= rinv;
            unsigned pk = (unsigned)bfbits(c0a) | ((unsigned)bfbits(c1a) << 16);
            stc32((unsigned*)wctxb + ((b * 512 + i0) >> 1), pk);
            *((unsigned*)XoutT + (((size_t)b * KOUT + 512 + i0) >> 1)) = pk;
        }
        gbar(cnt, 32u * (++bep));

        // ---- Phase D: cell0 ----
        {
            int j0 = bid * 16;
            stage_coh((const u64*)wctxb, As0);
            stage_coh((const u64*)(h0bd + cur * 16384), As1);
            __syncthreads();
            mfma_gates(As0, As1, dWih0wT, dWhh0T, j0, (float*)As0);
            cell_epi((float*)As0, Xembb + (size_t)t * 32 * 2048, nullptr,
                     c0d, (u64*)(h0bd + nxt * 16384), (u64*)(h0fd + nxt * 16384),
                     nullptr, 0, false, j0);
        }
        gbar(cnt, 32u * (++bep));

        // ---- Phase E: cell1 ----
        {
            int j0 = bid * 16;
            stage_coh((const u64*)(h0bd + nxt * 16384), As0);
            stage_coh((const u64*)(h1bd + cur * 16384), As1);
            __syncthreads();
            mfma_gates(As0, As1, dWih1T, dWhh1T, j0, (float*)As0);
            cell_epi((float*)As0, nullptr, db1,
                     c1d, (u64*)(h1bd + nxt * 16384), (u64*)(h1fd + nxt * 16384),
                     XoutT, KOUT, false, j0);
        }
        gbar(cnt, 32u * (++bep));
    }
}

// ============ generic MFMA GEMM: C(MxN) = A(MxK)bf16 @ BT(NxK)bf16 + bias ============
__global__ __launch_bounds__(256) void k_mfma(
    const __hip_bfloat16* __restrict__ A, const __hip_bfloat16* __restrict__ BT,
    const float* __restrict__ bias, float* __restrict__ Cf,
    __hip_bfloat16* __restrict__ Cb, int M, int N, int K)
{
    __shared__ __bf16 As[128][72];
    __shared__ __bf16 Bs[128][72];
    const unsigned short* Aw = (const unsigned short*)A;
    const unsigned short* Bw = (const unsigned short*)BT;
    int n0 = blockIdx.x * 128, m0 = blockIdx.y * 128;
    int tx = threadIdx.x;
    int w = tx >> 6, lane = tx & 63;
    int wm = (w >> 1) * 64, wn = (w & 1) * 64;
    int fr = lane & 15, kg = lane >> 4;
    f32x4 acc[4][4];
#pragma unroll
    for (int mi = 0; mi < 4; mi++)
#pragma unroll
        for (int ni = 0; ni < 4; ni++) acc[mi][ni] = (f32x4){0.f, 0.f, 0.f, 0.f};

    for (int k0 = 0; k0 < K; k0 += 64) {
        __syncthreads();
#pragma unroll
        for (int p = 0; p < 4; p++) {
            int ch = tx + p * 256;
            int r = ch >> 3, cc = (ch & 7) * 8;
            uint4 va = {0u, 0u, 0u, 0u};
            int m = m0 + r;
            if (m < M) va = *(const uint4*)(Aw + (size_t)m * K + k0 + cc);
            *(uint4*)(&As[r][cc]) = va;
            uint4 vb = *(const uint4*)(Bw + (size_t)(n0 + r) * K + k0 + cc);
            *(uint4*)(&Bs[r][cc]) = vb;
        }
        __syncthreads();
#pragma unroll
        for (int kk = 0; kk < 64; kk += 32) {
            bf16x8 af[4], bfv[4];
#pragma unroll
            for (int i = 0; i < 4; i++) {
                af[i]  = *(const bf16x8*)(&As[wm + i * 16 + fr][kk + kg * 8]);
                bfv[i] = *(const bf16x8*)(&Bs[wn + i * 16 + fr][kk + kg * 8]);
            }
#pragma unroll
            for (int mi = 0; mi < 4; mi++)
#pragma unroll
                for (int ni = 0; ni < 4; ni++)
                    acc[mi][ni] = __builtin_amdgcn_mfma_f32_16x16x32_bf16(
                        af[mi], bfv[ni], acc[mi][ni], 0, 0, 0);
        }
    }
#pragma unroll
    for (int ni = 0; ni < 4; ni++) {
        int n = n0 + wn + ni * 16 + fr;
        float bv = bias ? bias[n] : 0.f;
#pragma unroll
        for (int mi = 0; mi < 4; mi++) {
#pragma unroll
            for (int qd = 0; qd < 4; qd++) {
                int R = m0 + wm + mi * 16 + kg * 4 + qd;
                if (R < M) {
                    float v = acc[mi][ni][qd] + bv;
                    if (Cf) Cf[(size_t)R * N + n] = v;
                    else    Cb[(size_t)R * N + n] = __float2bfloat16(v);
                }
            }
        }
    }
}

// ============ small kernels ============
__global__ __launch_bounds__(256) void k_init_dec(
    const float* __restrict__ h0e, const float* __restrict__ h1e,
    const float* __restrict__ c0e, const float* __restrict__ c1e,
    float* __restrict__ h0fd, float* __restrict__ h1fd,
    __hip_bfloat16* __restrict__ h0bd, __hip_bfloat16* __restrict__ h1bd,
    float* __restrict__ c0d, float* __restrict__ c1d)
{
    int idx = blockIdx.x * 256 + threadIdx.x;
    float a = h0e[idx], b = h1e[idx];
    h0fd[idx] = a; h1fd[idx] = b;
    h0bd[idx] = __float2bfloat16(a);
    h1bd[idx] = __float2bfloat16(b);
    c0d[idx] = c0e[idx];
    c1d[idx] = c1e[idx];
}

__global__ __launch_bounds__(256) void k_bos(float* __restrict__ out)
{
    int b = blockIdx.y;
    int i = blockIdx.x * 256 + threadIdx.x;
    out[(size_t)b * (Tq * Vq) + i] = 2.0f;
}

__global__ __launch_bounds__(256) void k_finalize(
    const float* __restrict__ h0f, const float* __restrict__ h1f,
    const float* __restrict__ c0f, const float* __restrict__ c1f,
    float* __restrict__ out)
{
    int idx = blockIdx.x * 256 + threadIdx.x;
    size_t base = (size_t)Bq * Tq * Vq;
    out[base + idx] = h0f[idx];
    out[base + 16384 + idx] = h1f[idx];
    out[base + 32768 + idx] = c0f[idx];
    out[base + 49152 + idx] = c1f[idx];
}

// ============ logits GEMM (scatter epilogue) ============
__global__ __launch_bounds__(256) void k_logits(
    const __hip_bfloat16* __restrict__ A, const __hip_bfloat16* __restrict__ Bt,
    const float* __restrict__ bias, float* __restrict__ out)
{
    __shared__ __bf16 As[128][72];
    __shared__ __bf16 Bs[128][72];
    const unsigned short* Aw = (const unsigned short*)A;
    const unsigned short* Bw = (const unsigned short*)Bt;
    int n0 = blockIdx.x * 128, m0 = blockIdx.y * 128;
    int tx = threadIdx.x;
    int w = tx >> 6, lane = tx & 63;
    int wm = (w >> 1) * 64, wn = (w & 1) * 64;
    int fr = lane & 15, kg = lane >> 4;
    f32x4 acc[4][4];
#pragma unroll
    for (int mi = 0; mi < 4; mi++)
#pragma unroll
        for (int ni = 0; ni < 4; ni++) acc[mi][ni] = (f32x4){0.f, 0.f, 0.f, 0.f};

    for (int k0 = 0; k0 < 1280; k0 += 64) {
        __syncthreads();
#pragma unroll
        for (int p = 0; p < 4; p++) {
            int ch = tx + p * 256;
            int r = ch >> 3, cc = (ch & 7) * 8;
            uint4 va = {0u, 0u, 0u, 0u};
            int m = m0 + r;
            if (m < 2016) va = *(const uint4*)(Aw + (size_t)m * 1280 + k0 + cc);
            *(uint4*)(&As[r][cc]) = va;
            uint4 vb = *(const uint4*)(Bw + (size_t)(n0 + r) * 1280 + k0 + cc);
            *(uint4*)(&Bs[r][cc]) = vb;
        }
        __syncthreads();
#pragma unroll
        for (int kk = 0; kk < 64; kk += 32) {
            bf16x8 af[4], bfv[4];
#pragma unroll
            for (int i = 0; i < 4; i++) {
                af[i]  = *(const bf16x8*)(&As[wm + i * 16 + fr][kk + kg * 8]);
                bfv[i] = *(const bf16x8*)(&Bs[wn + i * 16 + fr][kk + kg * 8]);
            }
#pragma unroll
            for (int mi = 0; mi < 4; mi++)
#pragma unroll
                for (int ni = 0; ni < 4; ni++)
                    acc[mi][ni] = __builtin_amdgcn_mfma_f32_16x16x32_bf16(
                        af[mi], bfv[ni], acc[mi][ni], 0, 0, 0);
        }
    }
#pragma unroll
    for (int ni = 0; ni < 4; ni++) {
        int n = n0 + wn + ni * 16 + fr;
        float bv = bias[n];
#pragma unroll
        for (int mi = 0; mi < 4; mi++) {
#pragma unroll
            for (int qd = 0; qd < 4; qd++) {
                int R = m0 + wm + mi * 16 + kg * 4 + qd;
                if (R < 2016) {
                    int bb = R & 31, ts = R >> 5;
                    out[(size_t)bb * (Tq * Vq) + (size_t)(ts + 1) * Vq + n] =
                        acc[mi][ni][qd] + bv;
                }
            }
        }
    }
}

// ============ launcher ============
extern "C" void kernel_launch(void* const* d_in, const int* in_sizes, int n_in,
                              void* d_out, int out_size, void* d_ws, size_t ws_size,
                              hipStream_t stream)
{
    (void)in_sizes; (void)n_in; (void)out_size; (void)ws_size;
    const int*   src_tok = (const int*)  d_in[0];
    const int*   tgt_tok = (const int*)  d_in[1];
    const float* src_emb = (const float*)d_in[2];
    const float* tgt_emb = (const float*)d_in[3];
    const float* eWih0   = (const float*)d_in[4];
    const float* eWhh0   = (const float*)d_in[5];
    const float* eb0     = (const float*)d_in[6];
    const float* eWih1   = (const float*)d_in[7];
    const float* eWhh1   = (const float*)d_in[8];
    const float* eb1     = (const float*)d_in[9];
    const float* dWih0   = (const float*)d_in[10];
    const float* dWhh0   = (const float*)d_in[11];
    const float* db0     = (const float*)d_in[12];
    const float* dWih1   = (const float*)d_in[13];
    const float* dWhh1   = (const float*)d_in[14];
    const float* db1     = (const float*)d_in[15];
    const float* attn_W  = (const float*)d_in[16];
    const float* attn_b  = (const float*)d_in[17];
    const float* v_w     = (const float*)d_in[18];
    const float* coal_w  = (const float*)d_in[19];
    const float* coal_b  = (const float*)d_in[20];
    const float* out_W   = (const float*)d_in[21];
    const float* out_b   = (const float*)d_in[22];
    float* out = (float*)d_out;

    char* ws = (char*)d_ws;
    size_t off = 0;
    auto alloc = [&](size_t bytes) -> char* {
        char* p = ws + off;
        off += (bytes + 255) & ~(size_t)255;
        return p;
    };
    typedef __hip_bfloat16 BF;
    BF* X0b     = (BF*)alloc(4096ull * 2048 * 2);
    BF* Xembb   = (BF*)alloc(2016ull * 2048 * 2);
    BF* x_srcb  = (BF*)alloc(4096ull * 256 * 2);
    BF* embtb   = (BF*)alloc(2016ull * 256 * 2);
    BF* ys0b    = (BF*)alloc(128ull * 16384 * 2);
    BF* enc_outb  = (BF*)alloc(4096ull * 512 * 2);
    BF* enc_projb = (BF*)alloc(4096ull * 512 * 2);
    BF* wctxb     = (BF*)alloc(16384ull * 2);
    BF* Xout      = (BF*)alloc(2016ull * 1280 * 2);
    BF* Wt        = (BF*)alloc(32000ull * 1280 * 2);
    BF* eWhh0T  = (BF*)alloc(2048ull * 512 * 2);
    BF* eWih1T  = (BF*)alloc(2048ull * 512 * 2);
    BF* eWhh1T  = (BF*)alloc(2048ull * 512 * 2);
    BF* dWih0wT = (BF*)alloc(2048ull * 512 * 2);
    BF* dWhh0T  = (BF*)alloc(2048ull * 512 * 2);
    BF* dWih1T  = (BF*)alloc(2048ull * 512 * 2);
    BF* dWhh1T  = (BF*)alloc(2048ull * 512 * 2);
    BF* eWih0T  = (BF*)alloc(2048ull * 256 * 2);
    BF* dWih0eT = (BF*)alloc(2048ull * 256 * 2);
    BF* WqT     = (BF*)alloc(512ull * 512 * 2);
    BF* WeT     = (BF*)alloc(512ull * 512 * 2);
    BF* h0b_e   = (BF*)alloc(2ull * 16384 * 2);
    BF* h1b_e   = (BF*)alloc(2ull * 16384 * 2);
    float* h0f_e = (float*)alloc(16384ull * 4);
    float* h1f_e = (float*)alloc(16384ull * 4);
    float* c0e   = (float*)alloc(16384ull * 4);
    float* c1e   = (float*)alloc(16384ull * 4);
    float* h0fd  = (float*)alloc(2ull * 16384 * 4);
    float* h1fd  = (float*)alloc(2ull * 16384 * 4);
    BF* h0bd     = (BF*)alloc(2ull * 16384 * 2);
    BF* h1bd     = (BF*)alloc(2ull * 16384 * 2);
    float* c0d   = (float*)alloc(16384ull * 4);
    float* c1d   = (float*)alloc(16384ull * 4);
    unsigned* gbb = (unsigned*)alloc(256);

    hipMemsetAsync(gbb, 0, 256, stream);
    hipMemsetAsync(h0b_e, 0, 2 * 16384 * 2, stream);
    hipMemsetAsync(h1b_e, 0, 2 * 16384 * 2, stream);
    hipMemsetAsync(c0e, 0, 16384 * 4, stream);
    hipMemsetAsync(c1e, 0, 16384 * 4, stream);

    // embeddings
    k_embed_src<<<4096, 256, 0, stream>>>(src_tok, src_emb, x_srcb);
    k_embed_tgt<<<2016, 256, 0, stream>>>(tgt_tok, tgt_emb, embtb, Xout);

    // weight transposes (f32 -> bf16, N-major)
    k_transpose_bf16<<<dim3(64, 16), 256, 0, stream>>>(eWhh0, eWhh0T, 512, 2048);
    k_transpose_bf16<<<dim3(64, 16), 256, 0, stream>>>(eWih1, eWih1T, 512, 2048);
    k_transpose_bf16<<<dim3(64, 16), 256, 0, stream>>>(eWhh1, eWhh1T, 512, 2048);
    k_transpose_bf16<<<dim3(64, 16), 256, 0, stream>>>(dWih0 + 256 * 2048, dWih0wT, 512, 2048);
    k_transpose_bf16<<<dim3(64, 16), 256, 0, stream>>>(dWhh0, dWhh0T, 512, 2048);
    k_transpose_bf16<<<dim3(64, 16), 256, 0, stream>>>(dWih1, dWih1T, 512, 2048);
    k_transpose_bf16<<<dim3(64, 16), 256, 0, stream>>>(dWhh1, dWhh1T, 512, 2048);
    k_transpose_bf16<<<dim3(64, 8), 256, 0, stream>>>(eWih0, eWih0T, 256, 2048);
    k_transpose_bf16<<<dim3(64, 8), 256, 0, stream>>>(dWih0, dWih0eT, 256, 2048);
    k_transpose_bf16<<<dim3(16, 16), 256, 0, stream>>>(attn_W, WqT, 512, 512);
    k_transpose_bf16<<<dim3(16, 16), 256, 0, stream>>>(attn_W + 512 * 512, WeT, 512, 512);
    k_transpose_bf16<<<dim3(1000, 40), 256, 0, stream>>>(out_W, Wt, 1280, 32000);

    // input-side GEMMs (bf16 out)
    k_mfma<<<dim3(16, 32), 256, 0, stream>>>(x_srcb, eWih0T, eb0, nullptr, X0b, 4096, 2048, 256);
    k_mfma<<<dim3(16, 16), 256, 0, stream>>>(embtb, dWih0eT, db0, nullptr, Xembb, 2016, 2048, 256);
    k_bos<<<dim3(125, 32), 256, 0, stream>>>(out);

    // persistent encoder
    k_enc_persist<<<64, 256, 0, stream>>>(X0b, eWhh0T, eWih1T, eWhh1T, eb1,
                                          h0b_e, h1b_e, h0f_e, h1f_e, c0e, c1e,
                                          ys0b, enc_outb, gbb);

    // enc_proj = enc_out @ We (bf16 out)
    k_mfma<<<dim3(4, 32), 256, 0, stream>>>(enc_outb, WeT, nullptr, nullptr, enc_projb, 4096, 512, 512);

    k_init_dec<<<64, 256, 0, stream>>>(h0f_e, h1f_e, c0e, c1e,
                                       h0fd, h1fd, h0bd, h1bd, c0d, c1d);

    // persistent decoder
    k_dec_persist<<<32, 256, 0, stream>>>(enc_projb, enc_outb, src_tok, v_w,
                                          WqT, attn_b, coal_w, coal_b,
                                          dWih0wT, dWhh0T, dWih1T, dWhh1T,
                                          db1, Xembb,
                                          h0fd, h1fd, h0bd, h1bd, c0d, c1d,
                                          wctxb, Xout, gbb);

    k_finalize<<<64, 256, 0, stream>>>(h0fd + (TD & 1) * 16384, h1fd + (TD & 1) * 16384,
                                       c0d, c1d, out);
    k_logits<<<dim3(250, 16), 256, 0, stream>>>(Xout, Wt, out_b, out);
}

// Round 6
// 5559.715 us; speedup vs baseline: 1.4229x; 1.0530x over previous
//
#include <hip/hip_runtime.h>
#include <hip/hip_bf16.h>

typedef __bf16 bf16x8 __attribute__((ext_vector_type(8)));
typedef float f32x4 __attribute__((ext_vector_type(4)));
typedef unsigned long long u64;

#define DEV static __device__ __forceinline__

constexpr int Bq = 32, Sq = 128, Tq = 64, Eq = 256, Hq = 512, Vq = 32000;
constexpr int G4 = 2048;          // 4*H
constexpr int TD = 63;            // decode steps (T-1)
constexpr int KOUT = 1280;        // 2H + E
constexpr float SQRTE = 16.0f;    // sqrt(256)

DEV float sigf(float x) { return 1.0f / (1.0f + __expf(-x)); }
DEV float tanh_fast(float x) {
    float ax = fabsf(x);
    float t = __expf(-2.f * ax);
    float r = (1.f - t) / (1.f + t);
    return x < 0.f ? -r : r;
}
DEV float tanh_c(float x) {
    float xc = fminf(fmaxf(x, -15.f), 15.f);
    float t = __expf(2.f * xc);
    return (t - 1.f) / (t + 1.f);
}

// ---- coherent (agent-scope) access helpers ----
DEV u64 ldc(const u64* p) {
    return __hip_atomic_load(p, __ATOMIC_RELAXED, __HIP_MEMORY_SCOPE_AGENT);
}
DEV unsigned ldc32(const unsigned* p) {
    return __hip_atomic_load(p, __ATOMIC_RELAXED, __HIP_MEMORY_SCOPE_AGENT);
}
DEV void stc(u64* p, u64 v) {
    __hip_atomic_store(p, v, __ATOMIC_RELAXED, __HIP_MEMORY_SCOPE_AGENT);
}
DEV void stc32(unsigned* p, unsigned v) {
    __hip_atomic_store(p, v, __ATOMIC_RELAXED, __HIP_MEMORY_SCOPE_AGENT);
}
DEV unsigned short bfbits(float f) {
    __bf16 h = (__bf16)f;
    return __builtin_bit_cast(unsigned short, h);
}
DEV float bf2f(unsigned short u) {
    __bf16 h = __builtin_bit_cast(__bf16, u);
    return (float)h;
}
DEV u64 pack4bf(float a, float b, float c, float d) {
    return (u64)bfbits(a) | ((u64)bfbits(b) << 16) |
           ((u64)bfbits(c) << 32) | ((u64)bfbits(d) << 48);
}
DEV u64 pack2f(float a, float b) {
    return (u64)__float_as_uint(a) | ((u64)__float_as_uint(b) << 32);
}

// ---- contention-free global barrier: per-block padded flags, monotone epoch ----
// Each block owns one 128B-strided flag line (single writer). Wave 0 of every
// block polls all nblk flags as parallel per-lane loads to DISTINCT lines —
// no atomic RMW, no shared hot cacheline. __syncthreads() drains each wave's
// vmcnt before s_barrier, so all the block's stores retired before flag set.
DEV void gbar(unsigned* flags, int nblk, unsigned epoch) {
    __syncthreads();
    if (threadIdx.x < 64) {
        if (threadIdx.x == 0) {
            asm volatile("s_waitcnt vmcnt(0)" ::: "memory");
            stc32(flags + blockIdx.x * 32, epoch);
        }
        int lane = threadIdx.x;
        for (;;) {
            unsigned v = (lane < nblk) ? ldc32(flags + lane * 32) : 0xffffffffu;
            if (__all((int)(v >= epoch))) break;
            __builtin_amdgcn_s_sleep(1);
        }
    }
    __syncthreads();
}

// ============ embeddings (bf16 out) ============
__global__ __launch_bounds__(256) void k_embed_src(const int* __restrict__ tok,
                                                   const float* __restrict__ emb,
                                                   __hip_bfloat16* __restrict__ x)
{
    int idx = blockIdx.x * 256 + threadIdx.x;
    int e = idx & (Eq - 1);
    int r = idx >> 8;
    int b = r & 31, t = r >> 5;
    x[idx] = __float2bfloat16(emb[(size_t)tok[b * Sq + t] * Eq + e] * SQRTE);
}

__global__ __launch_bounds__(256) void k_embed_tgt(const int* __restrict__ tok,
                                                   const float* __restrict__ emb,
                                                   __hip_bfloat16* __restrict__ embt,
                                                   __hip_bfloat16* __restrict__ Xout)
{
    int idx = blockIdx.x * 256 + threadIdx.x;
    int e = idx & (Eq - 1);
    int r = idx >> 8;
    int b = r & 31, t = r >> 5;
    float v = fmaxf(0.f, emb[(size_t)tok[b * Tq + t] * Eq + e] * SQRTE);
    embt[idx] = __float2bfloat16(v);
    Xout[(size_t)r * KOUT + 1024 + e] = __float2bfloat16(v);
}

// ============ transpose + cast W (K x N) -> Wt (N x K) bf16 ============
__global__ __launch_bounds__(256) void k_transpose_bf16(const float* __restrict__ W,
                                                        __hip_bfloat16* __restrict__ Wt,
                                                        int K, int N)
{
    __shared__ float tile[32][33];
    int nb = blockIdx.x * 32, kb = blockIdx.y * 32;
    int c = threadIdx.x & 31, r4 = threadIdx.x >> 5;
    for (int i = 0; i < 32; i += 8)
        tile[r4 + i][c] = W[(size_t)(kb + r4 + i) * N + nb + c];
    __syncthreads();
    for (int i = 0; i < 32; i += 8) {
        int rr = r4 + i;
        Wt[(size_t)(nb + rr) * K + kb + c] = __float2bfloat16(tile[c][rr]);
    }
}

// ============ MFMA recurrent helpers (K=512, A=32x512 in LDS, swizzled) ============
DEV void stage_coh(const u64* src, __bf16* As) {
    int tx = threadIdx.x;
#pragma unroll
    for (int p = 0; p < 8; ++p) {
        int c = tx + p * 256;
        int row = c >> 6, kc = c & 63;
        u64 v0 = ldc(src + c * 2);
        u64 v1 = ldc(src + c * 2 + 1);
        int kd = kc ^ (row & 7);
        *(u64*)(As + row * 512 + kd * 8) = v0;
        *(u64*)(As + row * 512 + kd * 8 + 4) = v1;
    }
}

DEV void mfma_pass(const __bf16* As, const unsigned short* BT, int colB,
                   int kg, int fr, f32x4* acc) {
    const unsigned short* bp = BT + (size_t)colB * 512 + kg * 8;
    int f7 = fr & 7;
#pragma unroll
    for (int k0 = 0; k0 < 512; k0 += 32) {
        int cidx = ((k0 >> 3) | kg) ^ f7;
        bf16x8 bfv = *(const bf16x8*)(bp + k0);
        bf16x8 af0 = *(const bf16x8*)(As + fr * 512 + cidx * 8);
        bf16x8 af1 = *(const bf16x8*)(As + (16 + fr) * 512 + cidx * 8);
        acc[0] = __builtin_amdgcn_mfma_f32_16x16x32_bf16(af0, bfv, acc[0], 0, 0, 0);
        acc[1] = __builtin_amdgcn_mfma_f32_16x16x32_bf16(af1, bfv, acc[1], 0, 0, 0);
    }
}

DEV void mfma_gates(const __bf16* As0, const __bf16* As1,
                    const __hip_bfloat16* B0T, const __hip_bfloat16* B1T,
                    int j0, float* gbuf)
{
    int tx = threadIdx.x, w = tx >> 6, lane = tx & 63;
    int fr = lane & 15, kg = lane >> 4;
    int colB = w * 512 + j0 + fr;
    f32x4 acc[2];
    acc[0] = (f32x4){0.f, 0.f, 0.f, 0.f};
    acc[1] = (f32x4){0.f, 0.f, 0.f, 0.f};
    mfma_pass(As0, (const unsigned short*)B0T, colB, kg, fr, acc);
    if (B1T) mfma_pass(As1, (const unsigned short*)B1T, colB, kg, fr, acc);
    __syncthreads();
    float* gw = gbuf + w * 512;
#pragma unroll
    for (int m = 0; m < 2; ++m)
#pragma unroll
        for (int qd = 0; qd < 4; ++qd)
            gw[(m * 16 + kg * 4 + qd) * 16 + fr] = acc[m][qd];
    __syncthreads();
}

DEV void cell_epi(const float* gbuf, const __hip_bfloat16* xpart, const float* bias,
                  float* cbuf, u64* hb, u64* hf,
                  __hip_bfloat16* eb, int ebs, bool ebcoh,
                  int j0)
{
    int tx = threadIdx.x;
    if (tx >= 128) return;
    int b = tx >> 2, jg = tx & 3;
    int jj0 = jg * 4;
    int j = j0 + jj0;
    float g[4][4];
#pragma unroll
    for (int gi = 0; gi < 4; ++gi) {
        float4 gv = *(const float4*)(gbuf + gi * 512 + b * 16 + jj0);
        g[gi][0] = gv.x; g[gi][1] = gv.y; g[gi][2] = gv.z; g[gi][3] = gv.w;
        if (xpart) {
            u64 xv = *(const u64*)((const unsigned short*)xpart + b * 2048 + gi * 512 + j);
#pragma unroll
            for (int e = 0; e < 4; ++e)
                g[gi][e] += bf2f((unsigned short)(xv >> (16 * e)));
        }
        if (bias) {
            float4 bv = *(const float4*)(bias + gi * 512 + j);
            g[gi][0] += bv.x; g[gi][1] += bv.y; g[gi][2] += bv.z; g[gi][3] += bv.w;
        }
    }
    float4 cv = *(float4*)(cbuf + b * 512 + j);
    float cc[4] = {cv.x, cv.y, cv.z, cv.w};
    float hv[4];
#pragma unroll
    for (int e = 0; e < 4; ++e) {
        float cn = sigf(g[1][e]) * cc[e] + sigf(g[0][e]) * tanh_fast(g[2][e]);
        cc[e] = cn;
        hv[e] = sigf(g[3][e]) * tanh_fast(cn);
    }
    *(float4*)(cbuf + b * 512 + j) = make_float4(cc[0], cc[1], cc[2], cc[3]);
    u64 hpk = pack4bf(hv[0], hv[1], hv[2], hv[3]);
    stc(hb + ((b * 512 + j) >> 2), hpk);
    stc(hf + ((b * 512 + j) >> 1), pack2f(hv[0], hv[1]));
    stc(hf + ((b * 512 + j) >> 1) + 1, pack2f(hv[2], hv[3]));
    if (eb) {
        if (ebcoh) stc((u64*)(eb + (size_t)b * ebs + j), hpk);
        else       *(u64*)(eb + (size_t)b * ebs + j) = hpk;
    }
}

// ============ persistent encoder (64 blocks: 0-31 layer0 @t, 32-63 layer1 @t-1) ============
__global__ __launch_bounds__(256) void k_enc_persist(
    const __hip_bfloat16* __restrict__ X0b,
    const __hip_bfloat16* __restrict__ eWhh0T, const __hip_bfloat16* __restrict__ eWih1T,
    const __hip_bfloat16* __restrict__ eWhh1T, const float* __restrict__ eb1,
    __hip_bfloat16* __restrict__ h0b, __hip_bfloat16* __restrict__ h1b,
    float* __restrict__ h0f, float* __restrict__ h1f,
    float* __restrict__ c0, float* __restrict__ c1,
    __hip_bfloat16* __restrict__ ys0b,
    __hip_bfloat16* __restrict__ encb,
    unsigned* __restrict__ flags)
{
    __shared__ __align__(16) char shm[65536];
    __bf16* As0 = (__bf16*)shm;
    __bf16* As1 = (__bf16*)(shm + 32768);
    bool lay1 = blockIdx.x >= 32;
    int j0 = (blockIdx.x & 31) * 16;
    for (int t = 0; t <= 128; ++t) {
        if (!lay1) {
            if (t < 128) {
                stage_coh((const u64*)(h0b + (t & 1) * 16384), As0);
                __syncthreads();
                mfma_gates(As0, nullptr, eWhh0T, nullptr, j0, (float*)As0);
                cell_epi((float*)As0, X0b + (size_t)t * 32 * 2048, nullptr,
                         c0, (u64*)(h0b + ((t + 1) & 1) * 16384), (u64*)h0f,
                         ys0b + (size_t)t * 16384, 512, true, j0);
            }
        } else {
            if (t >= 1) {
                int s = t - 1;
                stage_coh((const u64*)(ys0b + (size_t)s * 16384), As0);
                stage_coh((const u64*)(h1b + (s & 1) * 16384), As1);
                __syncthreads();
                mfma_gates(As0, As1, eWih1T, eWhh1T, j0, (float*)As0);
                cell_epi((float*)As0, nullptr, eb1,
                         c1, (u64*)(h1b + ((s + 1) & 1) * 16384), (u64*)h1f,
                         encb + s * 512, 128 * 512, false, j0);
            }
        }
        gbar(flags, 64, (unsigned)(t + 1));
    }
}

// ============ persistent decoder (32 blocks, 63 steps x 3 phases) ============
__global__ __launch_bounds__(256) void k_dec_persist(
    const __hip_bfloat16* __restrict__ enc_projb, const __hip_bfloat16* __restrict__ enc_outb,
    const int* __restrict__ src_tok, const float* __restrict__ v_w,
    const __hip_bfloat16* __restrict__ WqT, const float* __restrict__ attn_b,
    const float* __restrict__ coal_w, const float* __restrict__ coal_b,
    const __hip_bfloat16* __restrict__ dWih0wT, const __hip_bfloat16* __restrict__ dWhh0T,
    const __hip_bfloat16* __restrict__ dWih1T, const __hip_bfloat16* __restrict__ dWhh1T,
    const float* __restrict__ db1, const __hip_bfloat16* __restrict__ Xembb,
    float* __restrict__ h0fd, float* __restrict__ h1fd,
    __hip_bfloat16* __restrict__ h0bd, __hip_bfloat16* __restrict__ h1bd,
    float* __restrict__ c0d, float* __restrict__ c1d,
    __hip_bfloat16* __restrict__ wctxb,
    __hip_bfloat16* __restrict__ Xout,
    unsigned* __restrict__ flags)
{
    __shared__ __align__(16) char shm[65536];
    __shared__ float rinvs;
    __bf16* As0 = (__bf16*)shm;
    __bf16* As1 = (__bf16*)(shm + 32768);
    int bid = blockIdx.x, tx = threadIdx.x;
    unsigned bep = 0;

    for (int t = 0; t < TD; ++t) {
        int cur = t & 1, nxt = cur ^ 1;
        __hip_bfloat16* XoutT = Xout + (size_t)t * 32 * KOUT;

        // ---- Phase B: full attention for batch row b = bid ----
        {
            int b = bid;
            float* q   = (float*)shm;          // 512
            float* aqs = q + 512;              // 512
            float* vws = aqs + 512;            // 512
            float* ws  = vws + 512;            // 128
            const float* hrow = (b < 16) ? (h0fd + cur * 16384 + b * 1024)
                                         : (h1fd + cur * 16384 + (b - 16) * 1024);
            float cw0 = coal_w[0], cw1 = coal_w[1], cb = coal_b[0];
            for (int j = tx; j < 512; j += 256) {
                u64 pv = ldc((const u64*)hrow + j);
                float v0 = __uint_as_float((unsigned)(pv & 0xffffffffu));
                float v1 = __uint_as_float((unsigned)(pv >> 32));
                q[j] = fmaxf(0.f, v0 * cw0 + v1 * cw1 + cb);
            }
            for (int i = tx; i < 512; i += 256) vws[i] = v_w[i];
            __syncthreads();
            // aq[i] = attn_b[i] + sum_j q[j] * Wq[j][i]   (WqT is i-major bf16)
            float a0 = attn_b[tx], a1 = attn_b[tx + 256];
            const unsigned short* w0 = (const unsigned short*)WqT + (size_t)tx * 512;
            const unsigned short* w1 = w0 + 256 * 512;
#pragma unroll 4
            for (int j8 = 0; j8 < 512; j8 += 8) {
                bf16x8 wa = *(const bf16x8*)(w0 + j8);
                bf16x8 wb = *(const bf16x8*)(w1 + j8);
#pragma unroll
                for (int e = 0; e < 8; ++e) {
                    float qe = q[j8 + e];
                    a0 += qe * (float)wa[e];
                    a1 += qe * (float)wb[e];
                }
            }
            aqs[tx] = a0; aqs[tx + 256] = a1;
            __syncthreads();
            // scores: 2 lanes per s, bf16 enc_proj
            int s = tx >> 1, half = tx & 1;
            const unsigned short* epr = (const unsigned short*)enc_projb
                                        + ((size_t)(b * 128 + s)) * 512 + half * 256;
            float s0 = 0.f, s1 = 0.f, s2 = 0.f, s3 = 0.f;
#pragma unroll 4
            for (int ii = 0; ii < 256; ii += 8) {
                bf16x8 f8 = *(const bf16x8*)(epr + ii);
                int ib = half * 256 + ii;
                s0 += tanh_c((float)f8[0] + aqs[ib])     * vws[ib];
                s1 += tanh_c((float)f8[1] + aqs[ib + 1]) * vws[ib + 1];
                s2 += tanh_c((float)f8[2] + aqs[ib + 2]) * vws[ib + 2];
                s3 += tanh_c((float)f8[3] + aqs[ib + 3]) * vws[ib + 3];
                s0 += tanh_c((float)f8[4] + aqs[ib + 4]) * vws[ib + 4];
                s1 += tanh_c((float)f8[5] + aqs[ib + 5]) * vws[ib + 5];
                s2 += tanh_c((float)f8[6] + aqs[ib + 6]) * vws[ib + 6];
                s3 += tanh_c((float)f8[7] + aqs[ib + 7]) * vws[ib + 7];
            }
            float p = (s0 + s1) + (s2 + s3);
            p += __shfl_xor(p, 1, 64);
            if (half == 0)
                ws[s] = (src_tok[b * 128 + s] != 1) ? __expf(p) : 0.f;
            __syncthreads();
            if (tx < 64) {
                float ss = ws[tx] + ws[tx + 64];
#pragma unroll
                for (int o = 32; o > 0; o >>= 1) ss += __shfl_down(ss, o, 64);
                if (tx == 0) rinvs = 1.0f / ss;
            }
            __syncthreads();
            float rinv = rinvs;
            // ctx: thread handles i0 = 2*tx, 2*tx+1 (bf16 enc_out)
            const unsigned short* eo = (const unsigned short*)enc_outb + (size_t)b * 65536;
            int i0 = tx * 2;
            float c0a = 0.f, c1a = 0.f;
#pragma unroll 4
            for (int s2i = 0; s2i < 128; ++s2i) {
                unsigned pk2 = *(const unsigned*)(eo + (size_t)s2i * 512 + i0);
                float wv = ws[s2i];
                c0a += wv * bf2f((unsigned short)(pk2 & 0xffffu));
                c1a += wv * bf2f((unsigned short)(pk2 >> 16));
            }
            c0a *= rinv; c1a *= rinv;
            unsigned pk = (unsigned)bfbits(c0a) | ((unsigned)bfbits(c1a) << 16);
            stc32((unsigned*)wctxb + ((b * 512 + i0) >> 1), pk);
            *((unsigned*)XoutT + (((size_t)b * KOUT + 512 + i0) >> 1)) = pk;
        }
        gbar(flags, 32, ++bep);

        // ---- Phase D: cell0 ----
        {
            int j0 = bid * 16;
            stage_coh((const u64*)wctxb, As0);
            stage_coh((const u64*)(h0bd + cur * 16384), As1);
            __syncthreads();
            mfma_gates(As0, As1, dWih0wT, dWhh0T, j0, (float*)As0);
            cell_epi((float*)As0, Xembb + (size_t)t * 32 * 2048, nullptr,
                     c0d, (u64*)(h0bd + nxt * 16384), (u64*)(h0fd + nxt * 16384),
                     nullptr, 0, false, j0);
        }
        gbar(flags, 32, ++bep);

        // ---- Phase E: cell1 ----
        {
            int j0 = bid * 16;
            stage_coh((const u64*)(h0bd + nxt * 16384), As0);
            stage_coh((const u64*)(h1bd + cur * 16384), As1);
            __syncthreads();
            mfma_gates(As0, As1, dWih1T, dWhh1T, j0, (float*)As0);
            cell_epi((float*)As0, nullptr, db1,
                     c1d, (u64*)(h1bd + nxt * 16384), (u64*)(h1fd + nxt * 16384),
                     XoutT, KOUT, false, j0);
        }
        gbar(flags, 32, ++bep);
    }
}

// ============ generic MFMA GEMM: C(MxN) = A(MxK)bf16 @ BT(NxK)bf16 + bias ============
__global__ __launch_bounds__(256) void k_mfma(
    const __hip_bfloat16* __restrict__ A, const __hip_bfloat16* __restrict__ BT,
    const float* __restrict__ bias, float* __restrict__ Cf,
    __hip_bfloat16* __restrict__ Cb, int M, int N, int K)
{
    __shared__ __bf16 As[128][72];
    __shared__ __bf16 Bs[128][72];
    const unsigned short* Aw = (const unsigned short*)A;
    const unsigned short* Bw = (const unsigned short*)BT;
    int n0 = blockIdx.x * 128, m0 = blockIdx.y * 128;
    int tx = threadIdx.x;
    int w = tx >> 6, lane = tx & 63;
    int wm = (w >> 1) * 64, wn = (w & 1) * 64;
    int fr = lane & 15, kg = lane >> 4;
    f32x4 acc[4][4];
#pragma unroll
    for (int mi = 0; mi < 4; mi++)
#pragma unroll
        for (int ni = 0; ni < 4; ni++) acc[mi][ni] = (f32x4){0.f, 0.f, 0.f, 0.f};

    for (int k0 = 0; k0 < K; k0 += 64) {
        __syncthreads();
#pragma unroll
        for (int p = 0; p < 4; p++) {
            int ch = tx + p * 256;
            int r = ch >> 3, cc = (ch & 7) * 8;
            uint4 va = {0u, 0u, 0u, 0u};
            int m = m0 + r;
            if (m < M) va = *(const uint4*)(Aw + (size_t)m * K + k0 + cc);
            *(uint4*)(&As[r][cc]) = va;
            uint4 vb = *(const uint4*)(Bw + (size_t)(n0 + r) * K + k0 + cc);
            *(uint4*)(&Bs[r][cc]) = vb;
        }
        __syncthreads();
#pragma unroll
        for (int kk = 0; kk < 64; kk += 32) {
            bf16x8 af[4], bfv[4];
#pragma unroll
            for (int i = 0; i < 4; i++) {
                af[i]  = *(const bf16x8*)(&As[wm + i * 16 + fr][kk + kg * 8]);
                bfv[i] = *(const bf16x8*)(&Bs[wn + i * 16 + fr][kk + kg * 8]);
            }
#pragma unroll
            for (int mi = 0; mi < 4; mi++)
#pragma unroll
                for (int ni = 0; ni < 4; ni++)
                    acc[mi][ni] = __builtin_amdgcn_mfma_f32_16x16x32_bf16(
                        af[mi], bfv[ni], acc[mi][ni], 0, 0, 0);
        }
    }
#pragma unroll
    for (int ni = 0; ni < 4; ni++) {
        int n = n0 + wn + ni * 16 + fr;
        float bv = bias ? bias[n] : 0.f;
#pragma unroll
        for (int mi = 0; mi < 4; mi++) {
#pragma unroll
            for (int qd = 0; qd < 4; qd++) {
                int R = m0 + wm + mi * 16 + kg * 4 + qd;
                if (R < M) {
                    float v = acc[mi][ni][qd] + bv;
                    if (Cf) Cf[(size_t)R * N + n] = v;
                    else    Cb[(size_t)R * N + n] = __float2bfloat16(v);
                }
            }
        }
    }
}

// ============ small kernels ============
__global__ __launch_bounds__(256) void k_init_dec(
    const float* __restrict__ h0e, const float* __restrict__ h1e,
    const float* __restrict__ c0e, const float* __restrict__ c1e,
    float* __restrict__ h0fd, float* __restrict__ h1fd,
    __hip_bfloat16* __restrict__ h0bd, __hip_bfloat16* __restrict__ h1bd,
    float* __restrict__ c0d, float* __restrict__ c1d)
{
    int idx = blockIdx.x * 256 + threadIdx.x;
    float a = h0e[idx], b = h1e[idx];
    h0fd[idx] = a; h1fd[idx] = b;
    h0bd[idx] = __float2bfloat16(a);
    h1bd[idx] = __float2bfloat16(b);
    c0d[idx] = c0e[idx];
    c1d[idx] = c1e[idx];
}

__global__ __launch_bounds__(256) void k_bos(float* __restrict__ out)
{
    int b = blockIdx.y;
    int i = blockIdx.x * 256 + threadIdx.x;
    out[(size_t)b * (Tq * Vq) + i] = 2.0f;
}

__global__ __launch_bounds__(256) void k_finalize(
    const float* __restrict__ h0f, const float* __restrict__ h1f,
    const float* __restrict__ c0f, const float* __restrict__ c1f,
    float* __restrict__ out)
{
    int idx = blockIdx.x * 256 + threadIdx.x;
    size_t base = (size_t)Bq * Tq * Vq;
    out[base + idx] = h0f[idx];
    out[base + 16384 + idx] = h1f[idx];
    out[base + 32768 + idx] = c0f[idx];
    out[base + 49152 + idx] = c1f[idx];
}

// ============ logits GEMM (scatter epilogue) ============
__global__ __launch_bounds__(256) void k_logits(
    const __hip_bfloat16* __restrict__ A, const __hip_bfloat16* __restrict__ Bt,
    const float* __restrict__ bias, float* __restrict__ out)
{
    __shared__ __bf16 As[128][72];
    __shared__ __bf16 Bs[128][72];
    const unsigned short* Aw = (const unsigned short*)A;
    const unsigned short* Bw = (const unsigned short*)Bt;
    int n0 = blockIdx.x * 128, m0 = blockIdx.y * 128;
    int tx = threadIdx.x;
    int w = tx >> 6, lane = tx & 63;
    int wm = (w >> 1) * 64, wn = (w & 1) * 64;
    int fr = lane & 15, kg = lane >> 4;
    f32x4 acc[4][4];
#pragma unroll
    for (int mi = 0; mi < 4; mi++)
#pragma unroll
        for (int ni = 0; ni < 4; ni++) acc[mi][ni] = (f32x4){0.f, 0.f, 0.f, 0.f};

    for (int k0 = 0; k0 < 1280; k0 += 64) {
        __syncthreads();
#pragma unroll
        for (int p = 0; p < 4; p++) {
            int ch = tx + p * 256;
            int r = ch >> 3, cc = (ch & 7) * 8;
            uint4 va = {0u, 0u, 0u, 0u};
            int m = m0 + r;
            if (m < 2016) va = *(const uint4*)(Aw + (size_t)m * 1280 + k0 + cc);
            *(uint4*)(&As[r][cc]) = va;
            uint4 vb = *(const uint4*)(Bw + (size_t)(n0 + r) * 1280 + k0 + cc);
            *(uint4*)(&Bs[r][cc]) = vb;
        }
        __syncthreads();
#pragma unroll
        for (int kk = 0; kk < 64; kk += 32) {
            bf16x8 af[4], bfv[4];
#pragma unroll
            for (int i = 0; i < 4; i++) {
                af[i]  = *(const bf16x8*)(&As[wm + i * 16 + fr][kk + kg * 8]);
                bfv[i] = *(const bf16x8*)(&Bs[wn + i * 16 + fr][kk + kg * 8]);
            }
#pragma unroll
            for (int mi = 0; mi < 4; mi++)
#pragma unroll
                for (int ni = 0; ni < 4; ni++)
                    acc[mi][ni] = __builtin_amdgcn_mfma_f32_16x16x32_bf16(
                        af[mi], bfv[ni], acc[mi][ni], 0, 0, 0);
        }
    }
#pragma unroll
    for (int ni = 0; ni < 4; ni++) {
        int n = n0 + wn + ni * 16 + fr;
        float bv = bias[n];
#pragma unroll
        for (int mi = 0; mi < 4; mi++) {
#pragma unroll
            for (int qd = 0; qd < 4; qd++) {
                int R = m0 + wm + mi * 16 + kg * 4 + qd;
                if (R < 2016) {
                    int bb = R & 31, ts = R >> 5;
                    out[(size_t)bb * (Tq * Vq) + (size_t)(ts + 1) * Vq + n] =
                        acc[mi][ni][qd] + bv;
                }
            }
        }
    }
}

// ============ launcher ============
extern "C" void kernel_launch(void* const* d_in, const int* in_sizes, int n_in,
                              void* d_out, int out_size, void* d_ws, size_t ws_size,
                              hipStream_t stream)
{
    (void)in_sizes; (void)n_in; (void)out_size; (void)ws_size;
    const int*   src_tok = (const int*)  d_in[0];
    const int*   tgt_tok = (const int*)  d_in[1];
    const float* src_emb = (const float*)d_in[2];
    const float* tgt_emb = (const float*)d_in[3];
    const float* eWih0   = (const float*)d_in[4];
    const float* eWhh0   = (const float*)d_in[5];
    const float* eb0     = (const float*)d_in[6];
    const float* eWih1   = (const float*)d_in[7];
    const float* eWhh1   = (const float*)d_in[8];
    const float* eb1     = (const float*)d_in[9];
    const float* dWih0   = (const float*)d_in[10];
    const float* dWhh0   = (const float*)d_in[11];
    const float* db0     = (const float*)d_in[12];
    const float* dWih1   = (const float*)d_in[13];
    const float* dWhh1   = (const float*)d_in[14];
    const float* db1     = (const float*)d_in[15];
    const float* attn_W  = (const float*)d_in[16];
    const float* attn_b  = (const float*)d_in[17];
    const float* v_w     = (const float*)d_in[18];
    const float* coal_w  = (const float*)d_in[19];
    const float* coal_b  = (const float*)d_in[20];
    const float* out_W   = (const float*)d_in[21];
    const float* out_b   = (const float*)d_in[22];
    float* out = (float*)d_out;

    char* ws = (char*)d_ws;
    size_t off = 0;
    auto alloc = [&](size_t bytes) -> char* {
        char* p = ws + off;
        off += (bytes + 255) & ~(size_t)255;
        return p;
    };
    typedef __hip_bfloat16 BF;
    BF* X0b     = (BF*)alloc(4096ull * 2048 * 2);
    BF* Xembb   = (BF*)alloc(2016ull * 2048 * 2);
    BF* x_srcb  = (BF*)alloc(4096ull * 256 * 2);
    BF* embtb   = (BF*)alloc(2016ull * 256 * 2);
    BF* ys0b    = (BF*)alloc(128ull * 16384 * 2);
    BF* enc_outb  = (BF*)alloc(4096ull * 512 * 2);
    BF* enc_projb = (BF*)alloc(4096ull * 512 * 2);
    BF* wctxb     = (BF*)alloc(16384ull * 2);
    BF* Xout      = (BF*)alloc(2016ull * 1280 * 2);
    BF* Wt        = (BF*)alloc(32000ull * 1280 * 2);
    BF* eWhh0T  = (BF*)alloc(2048ull * 512 * 2);
    BF* eWih1T  = (BF*)alloc(2048ull * 512 * 2);
    BF* eWhh1T  = (BF*)alloc(2048ull * 512 * 2);
    BF* dWih0wT = (BF*)alloc(2048ull * 512 * 2);
    BF* dWhh0T  = (BF*)alloc(2048ull * 512 * 2);
    BF* dWih1T  = (BF*)alloc(2048ull * 512 * 2);
    BF* dWhh1T  = (BF*)alloc(2048ull * 512 * 2);
    BF* eWih0T  = (BF*)alloc(2048ull * 256 * 2);
    BF* dWih0eT = (BF*)alloc(2048ull * 256 * 2);
    BF* WqT     = (BF*)alloc(512ull * 512 * 2);
    BF* WeT     = (BF*)alloc(512ull * 512 * 2);
    BF* h0b_e   = (BF*)alloc(2ull * 16384 * 2);
    BF* h1b_e   = (BF*)alloc(2ull * 16384 * 2);
    float* h0f_e = (float*)alloc(16384ull * 4);
    float* h1f_e = (float*)alloc(16384ull * 4);
    float* c0e   = (float*)alloc(16384ull * 4);
    float* c1e   = (float*)alloc(16384ull * 4);
    float* h0fd  = (float*)alloc(2ull * 16384 * 4);
    float* h1fd  = (float*)alloc(2ull * 16384 * 4);
    BF* h0bd     = (BF*)alloc(2ull * 16384 * 2);
    BF* h1bd     = (BF*)alloc(2ull * 16384 * 2);
    float* c0d   = (float*)alloc(16384ull * 4);
    float* c1d   = (float*)alloc(16384ull * 4);
    unsigned* encFlags = (unsigned*)alloc(64 * 32 * 4);   // 64 blocks x 128B
    unsigned* decFlags = (unsigned*)alloc(32 * 32 * 4);   // 32 blocks x 128B

    hipMemsetAsync(encFlags, 0, 64 * 32 * 4, stream);
    hipMemsetAsync(decFlags, 0, 32 * 32 * 4, stream);
    hipMemsetAsync(h0b_e, 0, 2 * 16384 * 2, stream);
    hipMemsetAsync(h1b_e, 0, 2 * 16384 * 2, stream);
    hipMemsetAsync(c0e, 0, 16384 * 4, stream);
    hipMemsetAsync(c1e, 0, 16384 * 4, stream);

    // embeddings
    k_embed_src<<<4096, 256, 0, stream>>>(src_tok, src_emb, x_srcb);
    k_embed_tgt<<<2016, 256, 0, stream>>>(tgt_tok, tgt_emb, embtb, Xout);

    // weight transposes (f32 -> bf16, N-major)
    k_transpose_bf16<<<dim3(64, 16), 256, 0, stream>>>(eWhh0, eWhh0T, 512, 2048);
    k_transpose_bf16<<<dim3(64, 16), 256, 0, stream>>>(eWih1, eWih1T, 512, 2048);
    k_transpose_bf16<<<dim3(64, 16), 256, 0, stream>>>(eWhh1, eWhh1T, 512, 2048);
    k_transpose_bf16<<<dim3(64, 16), 256, 0, stream>>>(dWih0 + 256 * 2048, dWih0wT, 512, 2048);
    k_transpose_bf16<<<dim3(64, 16), 256, 0, stream>>>(dWhh0, dWhh0T, 512, 2048);
    k_transpose_bf16<<<dim3(64, 16), 256, 0, stream>>>(dWih1, dWih1T, 512, 2048);
    k_transpose_bf16<<<dim3(64, 16), 256, 0, stream>>>(dWhh1, dWhh1T, 512, 2048);
    k_transpose_bf16<<<dim3(64, 8), 256, 0, stream>>>(eWih0, eWih0T, 256, 2048);
    k_transpose_bf16<<<dim3(64, 8), 256, 0, stream>>>(dWih0, dWih0eT, 256, 2048);
    k_transpose_bf16<<<dim3(16, 16), 256, 0, stream>>>(attn_W, WqT, 512, 512);
    k_transpose_bf16<<<dim3(16, 16), 256, 0, stream>>>(attn_W + 512 * 512, WeT, 512, 512);
    k_transpose_bf16<<<dim3(1000, 40), 256, 0, stream>>>(out_W, Wt, 1280, 32000);

    // input-side GEMMs (bf16 out)
    k_mfma<<<dim3(16, 32), 256, 0, stream>>>(x_srcb, eWih0T, eb0, nullptr, X0b, 4096, 2048, 256);
    k_mfma<<<dim3(16, 16), 256, 0, stream>>>(embtb, dWih0eT, db0, nullptr, Xembb, 2016, 2048, 256);
    k_bos<<<dim3(125, 32), 256, 0, stream>>>(out);

    // persistent encoder
    k_enc_persist<<<64, 256, 0, stream>>>(X0b, eWhh0T, eWih1T, eWhh1T, eb1,
                                          h0b_e, h1b_e, h0f_e, h1f_e, c0e, c1e,
                                          ys0b, enc_outb, encFlags);

    // enc_proj = enc_out @ We (bf16 out)
    k_mfma<<<dim3(4, 32), 256, 0, stream>>>(enc_outb, WeT, nullptr, nullptr, enc_projb, 4096, 512, 512);

    k_init_dec<<<64, 256, 0, stream>>>(h0f_e, h1f_e, c0e, c1e,
                                       h0fd, h1fd, h0bd, h1bd, c0d, c1d);

    // persistent decoder
    k_dec_persist<<<32, 256, 0, stream>>>(enc_projb, enc_outb, src_tok, v_w,
                                          WqT, attn_b, coal_w, coal_b,
                                          dWih0wT, dWhh0T, dWih1T, dWhh1T,
                                          db1, Xembb,
                                          h0fd, h1fd, h0bd, h1bd, c0d, c1d,
                                          wctxb, Xout, decFlags);

    k_finalize<<<64, 256, 0, stream>>>(h0fd + (TD & 1) * 16384, h1fd + (TD & 1) * 16384,
                                       c0d, c1d, out);
    k_logits<<<dim3(250, 16), 256, 0, stream>>>(Xout, Wt, out_b, out);
}